// Round 1
// baseline (2043.096 us; speedup 1.0000x reference)
//
#include <hip/hip_runtime.h>

#define NN 10000
#define NE 160000
#define NG 64
#define HID 128
#define NL 3

#define TE 32      // edges per block in k_edge
#define ZS 264     // padded row stride for Z / M1 tile
#define KC1 16     // K-chunk for edge GEMM staging
#define TN 16      // nodes per block in k_update
#define HS 264     // padded row stride for HA tile

__device__ __forceinline__ float fsig(float x){ return 1.f/(1.f+__expf(-x)); }

// ---------------- transpose weights [out][in] -> [in][out] ----------------
__global__ void k_transpose(const float* __restrict__ m1, const float* __restrict__ m2,
                            const float* __restrict__ mg,
                            float* __restrict__ wt1, float* __restrict__ wt2,
                            float* __restrict__ wtg){
  int i = blockIdx.x*256 + threadIdx.x;
  const int S1 = NL*257*256;
  const int S2 = NL*256*128;
  if (i < S1){
    int l = i/(257*256); int r = i - l*(257*256); int k = r>>8; int o = r&255;
    wt1[i] = m1[l*256*257 + o*257 + k];
  } else if (i < S1+S2){
    int j = i - S1;
    int l = j/(256*128); int r = j - l*(256*128); int k = r>>7; int o = r&127;
    wt2[j] = m2[l*128*256 + o*256 + k];
  } else if (i < S1+2*S2){
    int j = i - S1 - S2;
    int l = j/(256*128); int r = j - l*(256*128); int k = r>>7; int o = r&127;
    wtg[j] = mg[l*128*256 + o*256 + k];
  }
}

// ---------------- node embedding: h = silu(LN(x @ embW^T + b)) ----------------
__global__ void k_embed(const float* __restrict__ x, const float* __restrict__ W,
                        const float* __restrict__ b, const float* __restrict__ g,
                        const float* __restrict__ bb, float* __restrict__ h){
  const int n = blockIdx.x, c = threadIdx.x;
  __shared__ float red[4];
  float x0 = x[n*3+0], x1 = x[n*3+1], x2 = x[n*3+2];
  float v = W[c*3+0]*x0 + W[c*3+1]*x1 + W[c*3+2]*x2 + b[c];
  float s = v, s2 = v*v;
#pragma unroll
  for (int m=1;m<64;m<<=1){ s += __shfl_xor(s,m,64); s2 += __shfl_xor(s2,m,64); }
  if ((c & 63) == 0){ red[(c>>6)*2] = s; red[(c>>6)*2+1] = s2; }
  __syncthreads();
  float S = red[0]+red[2], S2 = red[1]+red[3];
  float mean = S*(1.f/128.f);
  float var = S2*(1.f/128.f) - mean*mean;
  float y = (v-mean)*rsqrtf(var+1e-5f)*g[c] + bb[c];
  h[(size_t)n*HID + c] = y * fsig(y);
}

// ---------------- edge MLP + scatter-add ----------------
// z = [h[dst], h[src], ea];  m1 = silu(z @ W1^T + b1);  m2 = m1 @ W2^T + b2
// aggr[dst] += m2   (atomic)
__global__ __launch_bounds__(256) void k_edge(
    const float* __restrict__ h, const float* __restrict__ ea,
    const int* __restrict__ ei,
    const float* __restrict__ wt1, const float* __restrict__ b1,   // wt1: [257][256]
    const float* __restrict__ wt2, const float* __restrict__ b2,   // wt2: [256][128]
    float* __restrict__ aggr)
{
  __shared__ float Z[TE][ZS];          // Z tile, later reused as M1 tile
  __shared__ float Wc[KC1*260];        // staged weight chunk
  __shared__ int sdst[TE];
  const int tid = threadIdx.x;
  const int e0 = blockIdx.x * TE;

  { // gather: 8 threads per edge, float4 rows
    int e = tid >> 3, q = tid & 7;
    int ge = e0 + e;
    int s = ei[ge];
    int d = ei[NE + ge];
    if (q == 0) sdst[e] = d;
    const float4* hs = (const float4*)(h + (size_t)s * HID);
    const float4* hd = (const float4*)(h + (size_t)d * HID);
    float4* z1 = (float4*)(&Z[e][0]);
    float4* z2 = (float4*)(&Z[e][128]);
#pragma unroll
    for (int i = 0; i < 4; i++){ z1[q + 8*i] = hd[q + 8*i]; z2[q + 8*i] = hs[q + 8*i]; }
    if (q == 7) Z[e][256] = ea[ge];
  }
  __syncthreads();

  const int tc = tid & 31, te = tid >> 5;
  const int skk = tid >> 4, sq = tid & 15;   // staging map (16 rows x 16 threads)

  // ---- GEMM1: [32 edges x 256 out], K = 256 (k=256 handled as rank-1 after) ----
  float acc[4][8];
#pragma unroll
  for (int i=0;i<4;i++)
#pragma unroll
    for (int j=0;j<8;j++) acc[i][j] = 0.f;

  for (int kc = 0; kc < 256; kc += KC1){
    {
      const float4* wr = (const float4*)(wt1 + (size_t)(kc + skk) * 256);
      float4* wl = (float4*)(&Wc[skk*260]);
#pragma unroll
      for (int i=0;i<4;i++) wl[sq + 16*i] = wr[sq + 16*i];
    }
    __syncthreads();
#pragma unroll
    for (int kk = 0; kk < KC1; kk++){
      float zv[4], wv[8];
#pragma unroll
      for (int i=0;i<4;i++) zv[i] = Z[te + 8*i][kc + kk];
#pragma unroll
      for (int j=0;j<8;j++) wv[j] = Wc[kk*260 + tc + 32*j];
#pragma unroll
      for (int i=0;i<4;i++)
#pragma unroll
        for (int j=0;j<8;j++) acc[i][j] += zv[i]*wv[j];
    }
    __syncthreads();
  }

  // edge_attr rank-1 term (k = 256) + bias + silu -> M1 (stored into Z tile)
  float w256[8], bb[8], eav[4];
#pragma unroll
  for (int j=0;j<8;j++){ w256[j] = wt1[256*256 + tc + 32*j]; bb[j] = b1[tc + 32*j]; }
#pragma unroll
  for (int i=0;i<4;i++) eav[i] = Z[te + 8*i][256];
#pragma unroll
  for (int i=0;i<4;i++)
#pragma unroll
    for (int j=0;j<8;j++){
      float v = acc[i][j] + eav[i]*w256[j] + bb[j];
      Z[te + 8*i][tc + 32*j] = v * fsig(v);       // silu; cols 0..255 only, col 256 untouched
    }
  __syncthreads();

  // ---- GEMM2: [32 edges x 128 out], K = 256 ----
  float acc2[4][4];
#pragma unroll
  for (int i=0;i<4;i++)
#pragma unroll
    for (int j=0;j<4;j++) acc2[i][j] = 0.f;

  for (int kc = 0; kc < 256; kc += KC1){
    {
      const float4* wr = (const float4*)(wt2 + (size_t)(kc + skk) * 128);
      float4* wl = (float4*)(&Wc[skk*132]);
#pragma unroll
      for (int i=0;i<2;i++) wl[sq + 16*i] = wr[sq + 16*i];
    }
    __syncthreads();
#pragma unroll
    for (int kk = 0; kk < KC1; kk++){
      float mv[4], wv[4];
#pragma unroll
      for (int i=0;i<4;i++) mv[i] = Z[te + 8*i][kc + kk];
#pragma unroll
      for (int j=0;j<4;j++) wv[j] = Wc[kk*132 + tc + 32*j];
#pragma unroll
      for (int i=0;i<4;i++)
#pragma unroll
        for (int j=0;j<4;j++) acc2[i][j] += mv[i]*wv[j];
    }
    __syncthreads();
  }

  float b2v[4];
#pragma unroll
  for (int j=0;j<4;j++) b2v[j] = b2[tc + 32*j];
#pragma unroll
  for (int i=0;i<4;i++){
    int d = sdst[te + 8*i];
#pragma unroll
    for (int j=0;j<4;j++)
      atomicAdd(&aggr[(size_t)d*HID + tc + 32*j], acc2[i][j] + b2v[j]);
  }
}

// ---------------- gate + residual + LN (in place on h) ----------------
__global__ __launch_bounds__(256) void k_update(
    const float* __restrict__ h, const float* __restrict__ aggr,
    const float* __restrict__ wtg, const float* __restrict__ gb,  // wtg: [256][128]
    const float* __restrict__ lng, const float* __restrict__ lnb,
    float* __restrict__ hout)
{
  __shared__ float HA[TN][HS];        // [n][k] : k<128 -> h, k>=128 -> aggr
  __shared__ float Wc[32*132];
  const int tid = threadIdx.x;
  const int n0 = blockIdx.x * TN;
  {
    int n = tid >> 4, q = tid & 15;
    const float4* hr = (const float4*)(h + (size_t)(n0+n)*HID);
    const float4* ar = (const float4*)(aggr + (size_t)(n0+n)*HID);
    float4* z1 = (float4*)(&HA[n][0]);
    float4* z2 = (float4*)(&HA[n][128]);
#pragma unroll
    for (int i=0;i<2;i++){ z1[q+16*i] = hr[q+16*i]; z2[q+16*i] = ar[q+16*i]; }
  }
  __syncthreads();
  const int tc = tid & 31, tn = tid >> 5;
  const int skk = tid >> 3, sq = tid & 7;
  float acc[2][4];
#pragma unroll
  for (int i=0;i<2;i++)
#pragma unroll
    for (int j=0;j<4;j++) acc[i][j] = 0.f;

  for (int kc = 0; kc < 256; kc += 32){
    {
      const float4* wr = (const float4*)(wtg + (size_t)(kc+skk)*128);
      float4* wl = (float4*)(&Wc[skk*132]);
#pragma unroll
      for (int i=0;i<4;i++) wl[sq+8*i] = wr[sq+8*i];
    }
    __syncthreads();
#pragma unroll
    for (int kk = 0; kk < 32; kk++){
      float hv[2], wv[4];
#pragma unroll
      for (int i=0;i<2;i++) hv[i] = HA[tn+8*i][kc+kk];
#pragma unroll
      for (int j=0;j<4;j++) wv[j] = Wc[kk*132 + tc+32*j];
#pragma unroll
      for (int i=0;i<2;i++)
#pragma unroll
        for (int j=0;j<4;j++) acc[i][j] += hv[i]*wv[j];
    }
    __syncthreads();
  }

  float gbv[4], gv[4], bv[4];
#pragma unroll
  for (int j=0;j<4;j++){ gbv[j]=gb[tc+32*j]; gv[j]=lng[tc+32*j]; bv[j]=lnb[tc+32*j]; }
#pragma unroll
  for (int i=0;i<2;i++){
    int n = n0 + tn + 8*i;
    float vv[4], s=0.f, s2=0.f;
#pragma unroll
    for (int j=0;j<4;j++){
      float gate = fsig(acc[i][j] + gbv[j]);
      float hvv = HA[tn+8*i][tc+32*j];
      float av  = HA[tn+8*i][128 + tc+32*j];
      float v = hvv + gate*av + (1.f-gate)*hvv;   // h + h_new
      vv[j]=v; s+=v; s2+=v*v;
    }
    // node n's 128 values live in one contiguous half-wave (32 lanes x 4 vals)
#pragma unroll
    for (int m=1;m<32;m<<=1){ s += __shfl_xor(s,m,64); s2 += __shfl_xor(s2,m,64); }
    float mean = s*(1.f/128.f);
    float var = s2*(1.f/128.f) - mean*mean;
    float rs = rsqrtf(var + 1e-5f);
#pragma unroll
    for (int j=0;j<4;j++)
      hout[(size_t)n*HID + tc+32*j] = (vv[j]-mean)*rs*gv[j] + bv[j];
  }
}

// ---------------- pooling: segmented sums (batch is sorted) ----------------
__global__ void k_pool(const float* __restrict__ h, const int* __restrict__ batch,
                       float* __restrict__ sums, float* __restrict__ counts){
  const int c = threadIdx.x;
  const int n0 = blockIdx.x * 8;
  int cur = batch[n0];
  float local = 0.f, cnt = 0.f;
  for (int i=0;i<8;i++){
    int n = n0 + i;
    int g = batch[n];
    if (g != cur){
      atomicAdd(&sums[cur*HID + c], local);
      if (c==0) atomicAdd(&counts[cur], cnt);
      local = 0.f; cnt = 0.f; cur = g;
    }
    local += h[(size_t)n*HID + c];
    cnt += 1.f;
  }
  atomicAdd(&sums[cur*HID + c], local);
  if (c==0) atomicAdd(&counts[cur], cnt);
}

// ---------------- x_global + projector ----------------
__global__ void k_final(const float* __restrict__ sums, const float* __restrict__ counts,
    const float* __restrict__ p1W, const float* __restrict__ p1b,
    const float* __restrict__ l1g, const float* __restrict__ l1b,
    const float* __restrict__ p2W, const float* __restrict__ p2b,
    const float* __restrict__ l2g, const float* __restrict__ l2b,
    float* __restrict__ out){
  const int g = blockIdx.x, c = threadIdx.x;
  __shared__ float xg[HID], p[HID], red[4];
  float cnt = counts[g];
  float s = sums[g*HID + c];
  float xgv = s * (1.f/fmaxf(cnt,1.f) + 1.f/(cnt + 1e-6f));
  out[NG*64 + g*HID + c] = xgv;          // x_global output (offset 4096)
  xg[c] = xgv;
  __syncthreads();
  float v = p1b[c];
  for (int k=0;k<HID;k++) v += xg[k]*p1W[c*HID + k];
  float sv=v, sv2=v*v;
#pragma unroll
  for (int m=1;m<64;m<<=1){ sv+=__shfl_xor(sv,m,64); sv2+=__shfl_xor(sv2,m,64); }
  if ((c&63)==0){ red[(c>>6)*2]=sv; red[(c>>6)*2+1]=sv2; }
  __syncthreads();
  float S=red[0]+red[2], S2=red[1]+red[3];
  float mean=S*(1.f/128.f), var=S2*(1.f/128.f)-mean*mean;
  float y=(v-mean)*rsqrtf(var+1e-5f)*l1g[c]+l1b[c];
  p[c] = y*fsig(y);
  __syncthreads();
  if (c < 64){
    float z = p2b[c];
    for (int k=0;k<HID;k++) z += p[k]*p2W[c*HID + k];
    float t=z, t2=z*z;
#pragma unroll
    for (int m=1;m<64;m<<=1){ t+=__shfl_xor(t,m,64); t2+=__shfl_xor(t2,m,64); }
    float mn=t*(1.f/64.f), vr=t2*(1.f/64.f)-mn*mn;
    out[g*64 + c] = (z-mn)*rsqrtf(vr+1e-5f)*l2g[c]+l2b[c];
  }
}

extern "C" void kernel_launch(void* const* d_in, const int* in_sizes, int n_in,
                              void* d_out, int out_size, void* d_ws, size_t ws_size,
                              hipStream_t stream){
  const float* x     = (const float*)d_in[0];
  const float* ea    = (const float*)d_in[1];
  const int*   ei    = (const int*)  d_in[2];
  const int*   batch = (const int*)  d_in[3];
  const float* embW  = (const float*)d_in[4];
  const float* embB  = (const float*)d_in[5];
  const float* embG  = (const float*)d_in[6];
  const float* embBe = (const float*)d_in[7];
  const float* m1W   = (const float*)d_in[8];
  const float* m1b   = (const float*)d_in[9];
  const float* m2W   = (const float*)d_in[10];
  const float* m2b   = (const float*)d_in[11];
  const float* gW    = (const float*)d_in[12];
  const float* gb    = (const float*)d_in[13];
  const float* lng   = (const float*)d_in[14];
  const float* lnb   = (const float*)d_in[15];
  const float* p1W   = (const float*)d_in[16];
  const float* p1b   = (const float*)d_in[17];
  const float* l1g   = (const float*)d_in[18];
  const float* l1b   = (const float*)d_in[19];
  const float* p2W   = (const float*)d_in[20];
  const float* p2b   = (const float*)d_in[21];
  const float* l2g   = (const float*)d_in[22];
  const float* l2b   = (const float*)d_in[23];

  float* ws   = (float*)d_ws;
  float* h    = ws;
  float* aggr = h + (size_t)NN*HID;
  float* wt1  = aggr + (size_t)NN*HID;
  float* wt2  = wt1 + NL*257*256;
  float* wtg  = wt2 + NL*256*128;
  float* sums = wtg + NL*256*128;
  float* counts = sums + NG*HID;

  const int S1 = NL*257*256, S2 = NL*256*128;
  k_transpose<<<(S1+2*S2+255)/256, 256, 0, stream>>>(m1W, m2W, gW, wt1, wt2, wtg);
  k_embed<<<NN, 128, 0, stream>>>(x, embW, embB, embG, embBe, h);
  for (int l=0; l<NL; l++){
    hipMemsetAsync(aggr, 0, (size_t)NN*HID*sizeof(float), stream);
    k_edge<<<NE/TE, 256, 0, stream>>>(h, ea, ei,
                                      wt1 + (size_t)l*257*256, m1b + l*256,
                                      wt2 + (size_t)l*256*128, m2b + l*128, aggr);
    k_update<<<NN/TN, 256, 0, stream>>>(h, aggr, wtg + (size_t)l*256*128, gb + l*128,
                                        lng + l*128, lnb + l*128, h);
  }
  hipMemsetAsync(sums, 0, (NG*HID + NG)*sizeof(float), stream);
  k_pool<<<NN/8, 128, 0, stream>>>(h, batch, sums, counts);
  k_final<<<NG, 128, 0, stream>>>(sums, counts, p1W, p1b, l1g, l1b,
                                  p2W, p2b, l2g, l2b, (float*)d_out);
}

// Round 2
// 1140.170 us; speedup vs baseline: 1.7919x; 1.7919x over previous
//
#include <hip/hip_runtime.h>

#define NN 10000
#define NE 160000
#define NG 64
#define HID 128
#define NL 3

#define TEB 64     // edges per block in k_edge
#define M1S 264    // padded row stride (bf16 elems) for M1 tile
#define TN 16      // nodes per block in k_update
#define HS 264     // padded row stride for HA tile

typedef float floatx4 __attribute__((ext_vector_type(4)));
typedef short bf16x8 __attribute__((ext_vector_type(8)));

__device__ __forceinline__ float fsig(float x){ return 1.f/(1.f+__expf(-x)); }

__device__ __forceinline__ short f2bf(float f){
  union { float f; unsigned u; } a; a.f = f;
  unsigned r = a.u + 0x7FFF + ((a.u >> 16) & 1);
  return (short)(r >> 16);
}

// ---------------- prep: cast weights to bf16 / transpose gate weights ----------------
__global__ void k_prep(const float* __restrict__ m1, const float* __restrict__ m2,
                       const float* __restrict__ mg,
                       short* __restrict__ w1bf, float* __restrict__ w256,
                       short* __restrict__ w2bf, float* __restrict__ wtg){
  int i = blockIdx.x*256 + threadIdx.x;
  const int A = NL*256*256;          // w1bf  (bf16 cast of [out][in 0..255])
  const int B = A + NL*256;          // w256  (fp32 column k=256)
  const int C = B + NL*128*256;      // w2bf  (bf16 cast, [out][in])
  const int D = C + NL*256*128;      // wtg   (fp32 transpose [in][out] for gate)
  if (i < A){
    int l = i>>16, r = i&65535, o = r>>8, k = r&255;
    w1bf[i] = f2bf(m1[l*65792 + o*257 + k]);
  } else if (i < B){
    int j = i-A; int l = j>>8, o = j&255;
    w256[j] = m1[l*65792 + o*257 + 256];
  } else if (i < C){
    int j = i-B;
    w2bf[j] = f2bf(m2[j]);
  } else if (i < D){
    int j = i-C; int l = j/32768, r = j&32767, k = r>>7, o = r&127;
    wtg[j] = mg[l*32768 + o*256 + k];
  }
}

// ---------------- node embedding: h = silu(LN(x @ embW^T + b)), + bf16 copy ----------------
__global__ void k_embed(const float* __restrict__ x, const float* __restrict__ W,
                        const float* __restrict__ b, const float* __restrict__ g,
                        const float* __restrict__ bb, float* __restrict__ h,
                        short* __restrict__ hbf){
  const int n = blockIdx.x, c = threadIdx.x;
  __shared__ float red[4];
  float x0 = x[n*3+0], x1 = x[n*3+1], x2 = x[n*3+2];
  float v = W[c*3+0]*x0 + W[c*3+1]*x1 + W[c*3+2]*x2 + b[c];
  float s = v, s2 = v*v;
#pragma unroll
  for (int m=1;m<64;m<<=1){ s += __shfl_xor(s,m,64); s2 += __shfl_xor(s2,m,64); }
  if ((c & 63) == 0){ red[(c>>6)*2] = s; red[(c>>6)*2+1] = s2; }
  __syncthreads();
  float S = red[0]+red[2], S2 = red[1]+red[3];
  float mean = S*(1.f/128.f);
  float var = S2*(1.f/128.f) - mean*mean;
  float y = (v-mean)*rsqrtf(var+1e-5f)*g[c] + bb[c];
  float o = y * fsig(y);
  h[(size_t)n*HID + c] = o;
  hbf[(size_t)n*HID + c] = f2bf(o);
}

// ---------------- edge MLP (bf16 MFMA) + scatter-add ----------------
// Computes transposed: C1[out][edge] = W1 @ Z^T ; M1 = silu(C1 + ea*w256 + b1)
//                      C2[out2][edge] = W2 @ M1^T ; atomicAdd into aggr[dst]
__global__ __launch_bounds__(256,4) void k_edge(
    const short* __restrict__ hbf, const float* __restrict__ ea,
    const int* __restrict__ ei,
    const short* __restrict__ w1, const float* __restrict__ w256,
    const float* __restrict__ b1,
    const short* __restrict__ w2, const float* __restrict__ b2,
    float* __restrict__ aggr)
{
  __shared__ short M1[TEB][M1S];     // [edge][out] bf16, padded
  const int tid = threadIdx.x;
  const int wv = tid >> 6, lane = tid & 63;
  const int col = lane & 15, quad = lane >> 4;
  const int e0 = blockIdx.x * TEB;

  // per-lane edge metadata for the 4 N-tiles (edge = e0 + nt*16 + col)
  int dstn[4], srcn[4];
  float eav[4];
#pragma unroll
  for (int nt=0; nt<4; nt++){
    int e = e0 + nt*16 + col;
    srcn[nt] = ei[e];
    dstn[nt] = ei[NE + e];
    eav[nt]  = ea[e];
  }

  // ---- GEMM1: wave wv handles out-tiles [wv*64, wv*64+64), all 64 edges ----
  floatx4 acc[4][4];
#pragma unroll
  for (int i=0;i<4;i++)
#pragma unroll
    for (int j=0;j<4;j++) acc[i][j] = (floatx4)(0.f);

#pragma unroll
  for (int kc = 0; kc < 256; kc += 32){
    bf16x8 bfrag[4];
#pragma unroll
    for (int nt=0; nt<4; nt++){
      int node = (kc < 128) ? dstn[nt] : srcn[nt];
      int ko = (kc & 127) + quad*8;
      bfrag[nt] = *(const bf16x8*)(hbf + (size_t)node*HID + ko);
    }
#pragma unroll
    for (int mt=0; mt<4; mt++){
      int mrow = (wv*4 + mt)*16 + col;
      bf16x8 afrag = *(const bf16x8*)(w1 + (size_t)mrow*256 + kc + quad*8);
#pragma unroll
      for (int nt=0; nt<4; nt++)
        acc[mt][nt] = __builtin_amdgcn_mfma_f32_16x16x32_bf16(afrag, bfrag[nt], acc[mt][nt], 0,0,0);
    }
  }

  // epilogue: bias + ea rank-1 + silu -> M1 bf16
#pragma unroll
  for (int mt=0; mt<4; mt++){
    int outb = (wv*4 + mt)*16 + quad*4;
    float4 b1v   = *(const float4*)(b1 + outb);
    float4 w256v = *(const float4*)(w256 + outb);
#pragma unroll
    for (int nt=0; nt<4; nt++){
      floatx4 c = acc[mt][nt];
      union { short s[4]; int2 v; } pk;
      float bb[4] = {b1v.x, b1v.y, b1v.z, b1v.w};
      float ww[4] = {w256v.x, w256v.y, w256v.z, w256v.w};
#pragma unroll
      for (int r=0;r<4;r++){
        float v = c[r] + eav[nt]*ww[r] + bb[r];
        pk.s[r] = f2bf(v * fsig(v));
      }
      *(int2*)(&M1[nt*16 + col][outb]) = pk.v;
    }
  }
  __syncthreads();

  // ---- GEMM2: wave wv handles out2-tiles [wv*32, wv*32+32), all 64 edges ----
  floatx4 acc2[2][4];
#pragma unroll
  for (int i=0;i<2;i++)
#pragma unroll
    for (int j=0;j<4;j++) acc2[i][j] = (floatx4)(0.f);

#pragma unroll
  for (int kc = 0; kc < 256; kc += 32){
    bf16x8 bfrag[4];
#pragma unroll
    for (int nt=0; nt<4; nt++)
      bfrag[nt] = *(const bf16x8*)(&M1[nt*16 + col][kc + quad*8]);
#pragma unroll
    for (int mt=0; mt<2; mt++){
      int mrow = (wv*2 + mt)*16 + col;
      bf16x8 afrag = *(const bf16x8*)(w2 + (size_t)mrow*256 + kc + quad*8);
#pragma unroll
      for (int nt=0; nt<4; nt++)
        acc2[mt][nt] = __builtin_amdgcn_mfma_f32_16x16x32_bf16(afrag, bfrag[nt], acc2[mt][nt], 0,0,0);
    }
  }

  // scatter: aggr[dst] += m2 (+b2 per edge)
#pragma unroll
  for (int mt=0; mt<2; mt++){
    int outb = (wv*2 + mt)*16 + quad*4;
    float4 b2v = *(const float4*)(b2 + outb);
    float bb[4] = {b2v.x, b2v.y, b2v.z, b2v.w};
#pragma unroll
    for (int nt=0; nt<4; nt++){
      float* p = aggr + (size_t)dstn[nt]*HID + outb;
#pragma unroll
      for (int r=0;r<4;r++)
        atomicAdd(p + r, acc2[mt][nt][r] + bb[r]);
    }
  }
}

// ---------------- gate + residual + LN (fp32), also emits bf16 copy ----------------
__global__ __launch_bounds__(256) void k_update(
    const float* __restrict__ h, const float* __restrict__ aggr,
    const float* __restrict__ wtg, const float* __restrict__ gb,  // wtg: [256][128]
    const float* __restrict__ lng, const float* __restrict__ lnb,
    float* __restrict__ hout, short* __restrict__ hbfout)
{
  __shared__ float HA[TN][HS];
  __shared__ float Wc[32*132];
  const int tid = threadIdx.x;
  const int n0 = blockIdx.x * TN;
  {
    int n = tid >> 4, q = tid & 15;
    const float4* hr = (const float4*)(h + (size_t)(n0+n)*HID);
    const float4* ar = (const float4*)(aggr + (size_t)(n0+n)*HID);
    float4* z1 = (float4*)(&HA[n][0]);
    float4* z2 = (float4*)(&HA[n][128]);
#pragma unroll
    for (int i=0;i<2;i++){ z1[q+16*i] = hr[q+16*i]; z2[q+16*i] = ar[q+16*i]; }
  }
  __syncthreads();
  const int tc = tid & 31, tn = tid >> 5;
  const int skk = tid >> 3, sq = tid & 7;
  float acc[2][4];
#pragma unroll
  for (int i=0;i<2;i++)
#pragma unroll
    for (int j=0;j<4;j++) acc[i][j] = 0.f;

  for (int kc = 0; kc < 256; kc += 32){
    {
      const float4* wr = (const float4*)(wtg + (size_t)(kc+skk)*128);
      float4* wl = (float4*)(&Wc[skk*132]);
#pragma unroll
      for (int i=0;i<4;i++) wl[sq+8*i] = wr[sq+8*i];
    }
    __syncthreads();
#pragma unroll
    for (int kk = 0; kk < 32; kk++){
      float hv[2], wv[4];
#pragma unroll
      for (int i=0;i<2;i++) hv[i] = HA[tn+8*i][kc+kk];
#pragma unroll
      for (int j=0;j<4;j++) wv[j] = Wc[kk*132 + tc+32*j];
#pragma unroll
      for (int i=0;i<2;i++)
#pragma unroll
        for (int j=0;j<4;j++) acc[i][j] += hv[i]*wv[j];
    }
    __syncthreads();
  }

  float gbv[4], gv[4], bv[4];
#pragma unroll
  for (int j=0;j<4;j++){ gbv[j]=gb[tc+32*j]; gv[j]=lng[tc+32*j]; bv[j]=lnb[tc+32*j]; }
#pragma unroll
  for (int i=0;i<2;i++){
    int n = n0 + tn + 8*i;
    float vv[4], s=0.f, s2=0.f;
#pragma unroll
    for (int j=0;j<4;j++){
      float gate = fsig(acc[i][j] + gbv[j]);
      float hvv = HA[tn+8*i][tc+32*j];
      float av  = HA[tn+8*i][128 + tc+32*j];
      float v = hvv + gate*av + (1.f-gate)*hvv;
      vv[j]=v; s+=v; s2+=v*v;
    }
#pragma unroll
    for (int m=1;m<32;m<<=1){ s += __shfl_xor(s,m,64); s2 += __shfl_xor(s2,m,64); }
    float mean = s*(1.f/128.f);
    float var = s2*(1.f/128.f) - mean*mean;
    float rs = rsqrtf(var + 1e-5f);
#pragma unroll
    for (int j=0;j<4;j++){
      float o = (vv[j]-mean)*rs*gv[j] + bv[j];
      hout[(size_t)n*HID + tc+32*j] = o;
      hbfout[(size_t)n*HID + tc+32*j] = f2bf(o);
    }
  }
}

// ---------------- pooling: segmented sums (batch is sorted) ----------------
__global__ void k_pool(const float* __restrict__ h, const int* __restrict__ batch,
                       float* __restrict__ sums, float* __restrict__ counts){
  const int c = threadIdx.x;
  const int n0 = blockIdx.x * 8;
  int cur = batch[n0];
  float local = 0.f, cnt = 0.f;
  for (int i=0;i<8;i++){
    int n = n0 + i;
    int g = batch[n];
    if (g != cur){
      atomicAdd(&sums[cur*HID + c], local);
      if (c==0) atomicAdd(&counts[cur], cnt);
      local = 0.f; cnt = 0.f; cur = g;
    }
    local += h[(size_t)n*HID + c];
    cnt += 1.f;
  }
  atomicAdd(&sums[cur*HID + c], local);
  if (c==0) atomicAdd(&counts[cur], cnt);
}

// ---------------- x_global + projector ----------------
__global__ void k_final(const float* __restrict__ sums, const float* __restrict__ counts,
    const float* __restrict__ p1W, const float* __restrict__ p1b,
    const float* __restrict__ l1g, const float* __restrict__ l1b,
    const float* __restrict__ p2W, const float* __restrict__ p2b,
    const float* __restrict__ l2g, const float* __restrict__ l2b,
    float* __restrict__ out){
  const int g = blockIdx.x, c = threadIdx.x;
  __shared__ float xg[HID], p[HID], red[4];
  float cnt = counts[g];
  float s = sums[g*HID + c];
  float xgv = s * (1.f/fmaxf(cnt,1.f) + 1.f/(cnt + 1e-6f));
  out[NG*64 + g*HID + c] = xgv;
  xg[c] = xgv;
  __syncthreads();
  float v = p1b[c];
  for (int k=0;k<HID;k++) v += xg[k]*p1W[c*HID + k];
  float sv=v, sv2=v*v;
#pragma unroll
  for (int m=1;m<64;m<<=1){ sv+=__shfl_xor(sv,m,64); sv2+=__shfl_xor(sv2,m,64); }
  if ((c&63)==0){ red[(c>>6)*2]=sv; red[(c>>6)*2+1]=sv2; }
  __syncthreads();
  float S=red[0]+red[2], S2=red[1]+red[3];
  float mean=S*(1.f/128.f), var=S2*(1.f/128.f)-mean*mean;
  float y=(v-mean)*rsqrtf(var+1e-5f)*l1g[c]+l1b[c];
  p[c] = y*fsig(y);
  __syncthreads();
  if (c < 64){
    float z = p2b[c];
    for (int k=0;k<HID;k++) z += p[k]*p2W[c*HID + k];
    float t=z, t2=z*z;
#pragma unroll
    for (int m=1;m<64;m<<=1){ t+=__shfl_xor(t,m,64); t2+=__shfl_xor(t2,m,64); }
    float mn=t*(1.f/64.f), vr=t2*(1.f/64.f)-mn*mn;
    out[g*64 + c] = (z-mn)*rsqrtf(vr+1e-5f)*l2g[c]+l2b[c];
  }
}

extern "C" void kernel_launch(void* const* d_in, const int* in_sizes, int n_in,
                              void* d_out, int out_size, void* d_ws, size_t ws_size,
                              hipStream_t stream){
  const float* x     = (const float*)d_in[0];
  const float* ea    = (const float*)d_in[1];
  const int*   ei    = (const int*)  d_in[2];
  const int*   batch = (const int*)  d_in[3];
  const float* embW  = (const float*)d_in[4];
  const float* embB  = (const float*)d_in[5];
  const float* embG  = (const float*)d_in[6];
  const float* embBe = (const float*)d_in[7];
  const float* m1W   = (const float*)d_in[8];
  const float* m1b   = (const float*)d_in[9];
  const float* m2W   = (const float*)d_in[10];
  const float* m2b   = (const float*)d_in[11];
  const float* gW    = (const float*)d_in[12];
  const float* gb    = (const float*)d_in[13];
  const float* lng   = (const float*)d_in[14];
  const float* lnb   = (const float*)d_in[15];
  const float* p1W   = (const float*)d_in[16];
  const float* p1b   = (const float*)d_in[17];
  const float* l1g   = (const float*)d_in[18];
  const float* l1b   = (const float*)d_in[19];
  const float* p2W   = (const float*)d_in[20];
  const float* p2b   = (const float*)d_in[21];
  const float* l2g   = (const float*)d_in[22];
  const float* l2b   = (const float*)d_in[23];

  float* ws   = (float*)d_ws;
  float* h    = ws;                                  // NN*128 fp32
  float* aggr = h + (size_t)NN*HID;                  // NN*128 fp32
  short* hbf  = (short*)(aggr + (size_t)NN*HID);     // NN*128 bf16
  float* base = (float*)(hbf + (size_t)NN*HID);
  short* w1bf = (short*)base;                        // NL*256*256 bf16
  float* w256 = base + (NL*256*256)/2;               // NL*256 fp32
  short* w2bf = (short*)(w256 + NL*256);             // NL*128*256 bf16
  float* wtg  = (float*)(w2bf) + (NL*128*256)/2;     // NL*256*128 fp32
  float* sums = wtg + NL*256*128;                    // NG*128
  float* counts = sums + NG*HID;                     // NG

  const int PT = NL*256*256 + NL*256 + NL*128*256 + NL*256*128;
  k_prep<<<(PT+255)/256, 256, 0, stream>>>(m1W, m2W, gW, w1bf, w256, w2bf, wtg);
  k_embed<<<NN, 128, 0, stream>>>(x, embW, embB, embG, embBe, h, hbf);
  for (int l=0; l<NL; l++){
    hipMemsetAsync(aggr, 0, (size_t)NN*HID*sizeof(float), stream);
    k_edge<<<NE/TEB, 256, 0, stream>>>(hbf, ea, ei,
                                       w1bf + (size_t)l*256*256, w256 + l*256, m1b + l*256,
                                       w2bf + (size_t)l*128*256, m2b + l*128, aggr);
    k_update<<<NN/TN, 256, 0, stream>>>(h, aggr, wtg + (size_t)l*256*128, gb + l*128,
                                        lng + l*128, lnb + l*128, h, hbf);
  }
  hipMemsetAsync(sums, 0, (NG*HID + NG)*sizeof(float), stream);
  k_pool<<<NN/8, 128, 0, stream>>>(h, batch, sums, counts);
  k_final<<<NG, 128, 0, stream>>>(sums, counts, p1W, p1b, l1g, l1b,
                                  p2W, p2b, l2g, l2b, (float*)d_out);
}

// Round 3
// 554.932 us; speedup vs baseline: 3.6817x; 2.0546x over previous
//
#include <hip/hip_runtime.h>

#define NN 10000
#define NNP 10048   // padded to 157*64
#define NE 160000
#define NG 64
#define HID 128
#define NL 3

#define TEB 64     // edges per block in k_edge
#define ZS 272     // LDS row stride (bf16) : 544 B = 16B-aligned, uniform bank groups
#define TNB 64     // nodes per block in k_update

typedef float floatx4 __attribute__((ext_vector_type(4)));
typedef short bf16x8 __attribute__((ext_vector_type(8)));

__device__ __forceinline__ float fsig(float x){ return 1.f/(1.f+__expf(-x)); }

__device__ __forceinline__ short f2bf(float f){
  union { float f; unsigned u; } a; a.f = f;
  unsigned r = a.u + 0x7FFF + ((a.u >> 16) & 1);
  return (short)(r >> 16);
}

// ---------------- prep: cast weights to bf16 ----------------
__global__ void k_prep(const float* __restrict__ m1, const float* __restrict__ m2,
                       const float* __restrict__ mg,
                       short* __restrict__ w1bf, float* __restrict__ w256,
                       short* __restrict__ w2bf, short* __restrict__ gwbf){
  int i = blockIdx.x*256 + threadIdx.x;
  const int A = NL*65536;            // w1bf  [l][out][k 0..255]
  const int B = A + NL*256;          // w256  fp32 column k=256
  const int C = B + NL*32768;        // w2bf
  const int D = C + NL*32768;        // gwbf
  if (i < A){
    int l = i>>16, r = i&65535, o = r>>8, k = r&255;
    w1bf[i] = f2bf(m1[l*65792 + o*257 + k]);
  } else if (i < B){
    int j = i-A; int l = j>>8, o = j&255;
    w256[j] = m1[l*65792 + o*257 + 256];
  } else if (i < C){
    int j = i-B;
    w2bf[j] = f2bf(m2[j]);
  } else if (i < D){
    int j = i-C;
    gwbf[j] = f2bf(mg[j]);
  }
}

// ---------------- CSR build ----------------
__global__ void k_hist(const int* __restrict__ ei, int* __restrict__ deg){
  int e = blockIdx.x*256 + threadIdx.x;
  atomicAdd(&deg[ei[NE + e]], 1);
}

__global__ void k_scan(const int* __restrict__ deg, int* __restrict__ rs){
  __shared__ int ps[257];
  const int t = threadIdx.x;
  const int base = t*40;
  int s = 0;
  for (int i=0;i<40;i++){ int idx=base+i; if (idx<NNP) s += deg[idx]; }
  ps[t+1] = s;
  __syncthreads();
  if (t==0){ ps[0]=0; for (int i=1;i<=256;i++) ps[i]+=ps[i-1]; }
  __syncthreads();
  int run = ps[t];
  for (int i=0;i<40;i++){ int idx=base+i; if (idx<NNP){ rs[idx]=run; run+=deg[idx]; } }
  if (t==255) rs[NNP] = ps[256];
}

__global__ void k_rank(const int* __restrict__ ei, const float* __restrict__ ea,
                       const int* __restrict__ rs, int* __restrict__ cursor,
                       int* __restrict__ esrc, int* __restrict__ edst,
                       float* __restrict__ eas){
  int e = blockIdx.x*256 + threadIdx.x;
  int d = ei[NE + e];
  int pos = rs[d] + atomicAdd(&cursor[d], 1);
  esrc[pos] = ei[e];
  edst[pos] = d;
  eas[pos]  = ea[e];
}

// ---------------- node embedding: h = silu(LN(x @ embW^T + b)), + bf16 copy ----------------
__global__ void k_embed(const float* __restrict__ x, const float* __restrict__ W,
                        const float* __restrict__ b, const float* __restrict__ g,
                        const float* __restrict__ bb, float* __restrict__ h,
                        short* __restrict__ hbf){
  const int n = blockIdx.x, c = threadIdx.x;
  __shared__ float red[4];
  float x0 = x[n*3+0], x1 = x[n*3+1], x2 = x[n*3+2];
  float v = W[c*3+0]*x0 + W[c*3+1]*x1 + W[c*3+2]*x2 + b[c];
  float s = v, s2 = v*v;
#pragma unroll
  for (int m=1;m<64;m<<=1){ s += __shfl_xor(s,m,64); s2 += __shfl_xor(s2,m,64); }
  if ((c & 63) == 0){ red[(c>>6)*2] = s; red[(c>>6)*2+1] = s2; }
  __syncthreads();
  float S = red[0]+red[2], S2 = red[1]+red[3];
  float mean = S*(1.f/128.f);
  float var = S2*(1.f/128.f) - mean*mean;
  float y = (v-mean)*rsqrtf(var+1e-5f)*g[c] + bb[c];
  float o = y * fsig(y);
  h[(size_t)n*HID + c] = o;
  hbf[(size_t)n*HID + c] = f2bf(o);
}

// ---------------- edge MLP (bf16 MFMA), sorted edges, fp16 msg store ----------------
__global__ __launch_bounds__(256,4) void k_edge(
    const short* __restrict__ hbf,
    const int* __restrict__ esrc, const int* __restrict__ edst,
    const float* __restrict__ eas,
    const short* __restrict__ w1, const float* __restrict__ w256,
    const float* __restrict__ b1,
    const short* __restrict__ w2, const float* __restrict__ b2,
    unsigned short* __restrict__ msg)
{
  __shared__ short Zs[TEB][ZS];      // Z tile; reused as M1 tile
  const int tid = threadIdx.x;
  const int wv = tid >> 6, lane = tid & 63;
  const int col = lane & 15, quad = lane >> 4;
  const int e0 = blockIdx.x * TEB;

  float eav[4];
#pragma unroll
  for (int nt=0; nt<4; nt++) eav[nt] = eas[e0 + nt*16 + col];

  { // stage Z: 4 threads per edge, 16B chunks; [0..127]=h[dst], [128..255]=h[src]
    int e = tid >> 2, q = tid & 3;
    int d = edst[e0+e], s = esrc[e0+e];
    const short* hd = hbf + (size_t)d * HID;
    const short* hs = hbf + (size_t)s * HID;
#pragma unroll
    for (int i=0;i<4;i++){
      int o = (q + 4*i) * 8;
      *(bf16x8*)(&Zs[e][o])       = *(const bf16x8*)(hd + o);
      *(bf16x8*)(&Zs[e][128 + o]) = *(const bf16x8*)(hs + o);
    }
  }
  __syncthreads();

  // ---- GEMM1: C1^T[out][edge], wave wv -> outs [wv*64, wv*64+64) ----
  floatx4 acc[4][4];
#pragma unroll
  for (int i=0;i<4;i++)
#pragma unroll
    for (int j=0;j<4;j++) acc[i][j] = (floatx4)(0.f);

#pragma unroll
  for (int kc = 0; kc < 256; kc += 32){
    bf16x8 bfrag[4];
#pragma unroll
    for (int nt=0; nt<4; nt++)
      bfrag[nt] = *(const bf16x8*)(&Zs[nt*16 + col][kc + quad*8]);
#pragma unroll
    for (int mt=0; mt<4; mt++){
      int mrow = (wv*4 + mt)*16 + col;
      bf16x8 afrag = *(const bf16x8*)(w1 + (size_t)mrow*256 + kc + quad*8);
#pragma unroll
      for (int nt=0; nt<4; nt++)
        acc[mt][nt] = __builtin_amdgcn_mfma_f32_16x16x32_bf16(afrag, bfrag[nt], acc[mt][nt], 0,0,0);
    }
  }
  __syncthreads();   // all waves done reading Zs

  // epilogue: bias + ea rank-1 + silu -> M1 (bf16, into Zs)
#pragma unroll
  for (int mt=0; mt<4; mt++){
    int outb = (wv*4 + mt)*16 + quad*4;
    float4 b1v   = *(const float4*)(b1 + outb);
    float4 w256v = *(const float4*)(w256 + outb);
    float bb[4] = {b1v.x, b1v.y, b1v.z, b1v.w};
    float ww[4] = {w256v.x, w256v.y, w256v.z, w256v.w};
#pragma unroll
    for (int nt=0; nt<4; nt++){
      union { short s[4]; int2 v; } pk;
#pragma unroll
      for (int r=0;r<4;r++){
        float v = acc[mt][nt][r] + eav[nt]*ww[r] + bb[r];
        pk.s[r] = f2bf(v * fsig(v));
      }
      *(int2*)(&Zs[nt*16 + col][outb]) = pk.v;
    }
  }
  __syncthreads();

  // ---- GEMM2: C2^T[out2][edge], wave wv -> outs [wv*32, wv*32+32) ----
  floatx4 acc2[2][4];
#pragma unroll
  for (int i=0;i<2;i++)
#pragma unroll
    for (int j=0;j<4;j++) acc2[i][j] = (floatx4)(0.f);

#pragma unroll
  for (int kc = 0; kc < 256; kc += 32){
    bf16x8 bfrag[4];
#pragma unroll
    for (int nt=0; nt<4; nt++)
      bfrag[nt] = *(const bf16x8*)(&Zs[nt*16 + col][kc + quad*8]);
#pragma unroll
    for (int mt=0; mt<2; mt++){
      int mrow = (wv*2 + mt)*16 + col;
      bf16x8 afrag = *(const bf16x8*)(w2 + (size_t)mrow*256 + kc + quad*8);
#pragma unroll
      for (int nt=0; nt<4; nt++)
        acc2[mt][nt] = __builtin_amdgcn_mfma_f32_16x16x32_bf16(afrag, bfrag[nt], acc2[mt][nt], 0,0,0);
    }
  }

  // store msg (fp16) at sorted row = e0 + nt*16 + col
#pragma unroll
  for (int mt=0; mt<2; mt++){
    int outb = (wv*2 + mt)*16 + quad*4;
    float4 b2v = *(const float4*)(b2 + outb);
    float bb[4] = {b2v.x, b2v.y, b2v.z, b2v.w};
#pragma unroll
    for (int nt=0; nt<4; nt++){
      union { _Float16 hx[4]; uint2 u; } pk;
#pragma unroll
      for (int r=0;r<4;r++)
        pk.hx[r] = (_Float16)(acc2[mt][nt][r] + bb[r]);
      *(uint2*)(msg + (size_t)(e0 + nt*16 + col)*HID + outb) = pk.u;
    }
  }
}

// ---------------- fused aggregation + gate MFMA + residual + LN ----------------
__global__ __launch_bounds__(256,2) void k_update(
    const short* __restrict__ hbf, const float* __restrict__ h,
    const unsigned short* __restrict__ msg, const int* __restrict__ rs,
    const short* __restrict__ gw, const float* __restrict__ gb,
    const float* __restrict__ lng, const float* __restrict__ lnb,
    float* __restrict__ hout, short* __restrict__ hbfout)
{
  __shared__ short HB[TNB][ZS];       // [node][k] bf16: k<128 h, k>=128 aggr
  __shared__ float Agg[TNB][132];     // fp32 aggregation
  __shared__ float reds[4][TNB], reds2[4][TNB];
  const int tid = threadIdx.x;
  const int wv = tid >> 6, lane = tid & 63;
  const int col = lane & 15, quad = lane >> 4;
  const int n0 = blockIdx.x * TNB;

  { // stage h rows (bf16 copy)
    int n = tid >> 2, q = tid & 3;
    const short* hr = hbf + (size_t)(n0+n)*HID;
#pragma unroll
    for (int i=0;i<4;i++){
      int o = (q + 4*i) * 8;
      *(bf16x8*)(&HB[n][o]) = *(const bf16x8*)(hr + o);
    }
  }
  { // aggregate msg rows (CSR), fp32 -> Agg + bf16 -> HB[.][128..]
    int q = tid & 15, nr = tid >> 4;
    for (int no=0; no<4; no++){
      int n = no*16 + nr;
      int gn = n0 + n;
      float a[8];
#pragma unroll
      for (int j=0;j<8;j++) a[j] = 0.f;
      int rb = rs[gn], re = rs[gn+1];
      for (int r=rb; r<re; r++){
        union { uint4 u; _Float16 hx[8]; } ld;
        ld.u = *(const uint4*)(msg + (size_t)r*HID + q*8);
#pragma unroll
        for (int j=0;j<8;j++) a[j] += (float)ld.hx[j];
      }
      *(float4*)(&Agg[n][q*8])   = make_float4(a[0],a[1],a[2],a[3]);
      *(float4*)(&Agg[n][q*8+4]) = make_float4(a[4],a[5],a[6],a[7]);
      union { short s[8]; bf16x8 v; } pk;
#pragma unroll
      for (int j=0;j<8;j++) pk.s[j] = f2bf(a[j]);
      *(bf16x8*)(&HB[n][128 + q*8]) = pk.v;
    }
  }
  __syncthreads();

  // gate GEMM: C^T[out][node], wave wv -> outs [wv*32, wv*32+32)
  floatx4 acc[2][4];
#pragma unroll
  for (int i=0;i<2;i++)
#pragma unroll
    for (int j=0;j<4;j++) acc[i][j] = (floatx4)(0.f);

#pragma unroll
  for (int kc = 0; kc < 256; kc += 32){
    bf16x8 bfrag[4];
#pragma unroll
    for (int nt=0; nt<4; nt++)
      bfrag[nt] = *(const bf16x8*)(&HB[nt*16 + col][kc + quad*8]);
#pragma unroll
    for (int mt=0; mt<2; mt++){
      int mrow = (wv*2 + mt)*16 + col;
      bf16x8 afrag = *(const bf16x8*)(gw + (size_t)mrow*256 + kc + quad*8);
#pragma unroll
      for (int nt=0; nt<4; nt++)
        acc[mt][nt] = __builtin_amdgcn_mfma_f32_16x16x32_bf16(afrag, bfrag[nt], acc[mt][nt], 0,0,0);
    }
  }

  // epilogue: gate, residual; partial LN sums
  float vv[2][4][4];
  float s[4], s2[4];
#pragma unroll
  for (int nt=0;nt<4;nt++){ s[nt]=0.f; s2[nt]=0.f; }
#pragma unroll
  for (int mt=0; mt<2; mt++){
    int outb = (wv*2 + mt)*16 + quad*4;
    float4 gbv = *(const float4*)(gb + outb);
    float gg[4] = {gbv.x, gbv.y, gbv.z, gbv.w};
#pragma unroll
    for (int nt=0; nt<4; nt++){
      int node = n0 + nt*16 + col;
      float4 hv = *(const float4*)(h + (size_t)node*HID + outb);
      float4 av = *(const float4*)(&Agg[nt*16 + col][outb]);
      float hh[4] = {hv.x, hv.y, hv.z, hv.w};
      float aa[4] = {av.x, av.y, av.z, av.w};
#pragma unroll
      for (int r=0;r<4;r++){
        float gate = fsig(acc[mt][nt][r] + gg[r]);
        float v = hh[r] + gate*aa[r] + (1.f-gate)*hh[r];
        vv[mt][nt][r] = v; s[nt] += v; s2[nt] += v*v;
      }
    }
  }
  // reduce across quads (lanes xor 16, 32)
#pragma unroll
  for (int nt=0; nt<4; nt++){
    s[nt]  += __shfl_xor(s[nt], 16, 64);  s[nt]  += __shfl_xor(s[nt], 32, 64);
    s2[nt] += __shfl_xor(s2[nt], 16, 64); s2[nt] += __shfl_xor(s2[nt], 32, 64);
  }
  if (quad == 0){
#pragma unroll
    for (int nt=0; nt<4; nt++){ reds[wv][nt*16+col] = s[nt]; reds2[wv][nt*16+col] = s2[nt]; }
  }
  __syncthreads();

#pragma unroll
  for (int nt=0; nt<4; nt++){
    int nl = nt*16 + col;
    float S  = reds[0][nl]+reds[1][nl]+reds[2][nl]+reds[3][nl];
    float S2 = reds2[0][nl]+reds2[1][nl]+reds2[2][nl]+reds2[3][nl];
    float mean = S*(1.f/128.f);
    float var  = S2*(1.f/128.f) - mean*mean;
    float rsq  = rsqrtf(var + 1e-5f);
    int node = n0 + nl;
#pragma unroll
    for (int mt=0; mt<2; mt++){
      int outb = (wv*2 + mt)*16 + quad*4;
      float4 gv = *(const float4*)(lng + outb);
      float4 bv = *(const float4*)(lnb + outb);
      float gvl[4] = {gv.x, gv.y, gv.z, gv.w};
      float bvl[4] = {bv.x, bv.y, bv.z, bv.w};
      float4 outv;
      union { short sh[4]; int2 v; } pk;
      float* ov = (float*)&outv;
#pragma unroll
      for (int r=0;r<4;r++){
        float o = (vv[mt][nt][r]-mean)*rsq*gvl[r] + bvl[r];
        ov[r] = o; pk.sh[r] = f2bf(o);
      }
      *(float4*)(hout + (size_t)node*HID + outb) = outv;
      *(int2*)(hbfout + (size_t)node*HID + outb) = pk.v;
    }
  }
}

// ---------------- pooling: segmented sums (batch is sorted) ----------------
__global__ void k_pool(const float* __restrict__ h, const int* __restrict__ batch,
                       float* __restrict__ sums, float* __restrict__ counts){
  const int c = threadIdx.x;
  const int n0 = blockIdx.x * 8;
  int cur = batch[n0];
  float local = 0.f, cnt = 0.f;
  for (int i=0;i<8;i++){
    int n = n0 + i;
    int g = batch[n];
    if (g != cur){
      atomicAdd(&sums[cur*HID + c], local);
      if (c==0) atomicAdd(&counts[cur], cnt);
      local = 0.f; cnt = 0.f; cur = g;
    }
    local += h[(size_t)n*HID + c];
    cnt += 1.f;
  }
  atomicAdd(&sums[cur*HID + c], local);
  if (c==0) atomicAdd(&counts[cur], cnt);
}

// ---------------- x_global + projector ----------------
__global__ void k_final(const float* __restrict__ sums, const float* __restrict__ counts,
    const float* __restrict__ p1W, const float* __restrict__ p1b,
    const float* __restrict__ l1g, const float* __restrict__ l1b,
    const float* __restrict__ p2W, const float* __restrict__ p2b,
    const float* __restrict__ l2g, const float* __restrict__ l2b,
    float* __restrict__ out){
  const int g = blockIdx.x, c = threadIdx.x;
  __shared__ float xg[HID], p[HID], red[4];
  float cnt = counts[g];
  float s = sums[g*HID + c];
  float xgv = s * (1.f/fmaxf(cnt,1.f) + 1.f/(cnt + 1e-6f));
  out[NG*64 + g*HID + c] = xgv;
  xg[c] = xgv;
  __syncthreads();
  float v = p1b[c];
  for (int k=0;k<HID;k++) v += xg[k]*p1W[c*HID + k];
  float sv=v, sv2=v*v;
#pragma unroll
  for (int m=1;m<64;m<<=1){ sv+=__shfl_xor(sv,m,64); sv2+=__shfl_xor(sv2,m,64); }
  if ((c&63)==0){ red[(c>>6)*2]=sv; red[(c>>6)*2+1]=sv2; }
  __syncthreads();
  float S=red[0]+red[2], S2=red[1]+red[3];
  float mean=S*(1.f/128.f), var=S2*(1.f/128.f)-mean*mean;
  float y=(v-mean)*rsqrtf(var+1e-5f)*l1g[c]+l1b[c];
  p[c] = y*fsig(y);
  __syncthreads();
  if (c < 64){
    float z = p2b[c];
    for (int k=0;k<HID;k++) z += p[k]*p2W[c*HID + k];
    float t=z, t2=z*z;
#pragma unroll
    for (int m=1;m<64;m<<=1){ t+=__shfl_xor(t,m,64); t2+=__shfl_xor(t2,m,64); }
    float mn=t*(1.f/64.f), vr=t2*(1.f/64.f)-mn*mn;
    out[g*64 + c] = (z-mn)*rsqrtf(vr+1e-5f)*l2g[c]+l2b[c];
  }
}

extern "C" void kernel_launch(void* const* d_in, const int* in_sizes, int n_in,
                              void* d_out, int out_size, void* d_ws, size_t ws_size,
                              hipStream_t stream){
  const float* x     = (const float*)d_in[0];
  const float* ea    = (const float*)d_in[1];
  const int*   ei    = (const int*)  d_in[2];
  const int*   batch = (const int*)  d_in[3];
  const float* embW  = (const float*)d_in[4];
  const float* embB  = (const float*)d_in[5];
  const float* embG  = (const float*)d_in[6];
  const float* embBe = (const float*)d_in[7];
  const float* m1W   = (const float*)d_in[8];
  const float* m1b   = (const float*)d_in[9];
  const float* m2W   = (const float*)d_in[10];
  const float* m2b   = (const float*)d_in[11];
  const float* gW    = (const float*)d_in[12];
  const float* gb    = (const float*)d_in[13];
  const float* lng   = (const float*)d_in[14];
  const float* lnb   = (const float*)d_in[15];
  const float* p1W   = (const float*)d_in[16];
  const float* p1b   = (const float*)d_in[17];
  const float* l1g   = (const float*)d_in[18];
  const float* l1b   = (const float*)d_in[19];
  const float* p2W   = (const float*)d_in[20];
  const float* p2b   = (const float*)d_in[21];
  const float* l2g   = (const float*)d_in[22];
  const float* l2b   = (const float*)d_in[23];

  char* p = (char*)d_ws;
  auto alloc = [&](size_t bytes){ char* r = p; p += (bytes + 255) & ~(size_t)255; return r; };
  float* h    = (float*) alloc((size_t)NNP*HID*4);
  short* hbf  = (short*) alloc((size_t)NNP*HID*2);
  unsigned short* msg = (unsigned short*) alloc((size_t)NE*HID*2);
  short* w1bf = (short*) alloc((size_t)NL*65536*2);
  float* w256 = (float*) alloc((size_t)NL*256*4);
  short* w2bf = (short*) alloc((size_t)NL*32768*2);
  short* gwbf = (short*) alloc((size_t)NL*32768*2);
  int* deg    = (int*)   alloc((size_t)NNP*4);
  int* cursor = (int*)   alloc((size_t)NNP*4);
  int* rs     = (int*)   alloc((size_t)(NNP+1)*4);
  int* esrc   = (int*)   alloc((size_t)NE*4);
  int* edst   = (int*)   alloc((size_t)NE*4);
  float* eas  = (float*) alloc((size_t)NE*4);
  float* sums = (float*) alloc((size_t)NG*HID*4);
  float* counts=(float*) alloc((size_t)NG*4);

  hipMemsetAsync(deg, 0, (size_t)NNP*4, stream);
  hipMemsetAsync(cursor, 0, (size_t)NNP*4, stream);
  hipMemsetAsync(sums, 0, (size_t)NG*HID*4, stream);
  hipMemsetAsync(counts, 0, (size_t)NG*4, stream);

  const int PT = NL*131328;
  k_prep<<<(PT+255)/256, 256, 0, stream>>>(m1W, m2W, gW, w1bf, w256, w2bf, gwbf);
  k_embed<<<NN, 128, 0, stream>>>(x, embW, embB, embG, embBe, h, hbf);
  k_hist<<<NE/256, 256, 0, stream>>>(ei, deg);
  k_scan<<<1, 256, 0, stream>>>(deg, rs);
  k_rank<<<NE/256, 256, 0, stream>>>(ei, ea, rs, cursor, esrc, edst, eas);

  for (int l=0; l<NL; l++){
    k_edge<<<NE/TEB, 256, 0, stream>>>(hbf, esrc, edst, eas,
                                       w1bf + (size_t)l*65536, w256 + l*256, m1b + l*256,
                                       w2bf + (size_t)l*32768, m2b + l*128, msg);
    k_update<<<NNP/TNB, 256, 0, stream>>>(hbf, h, msg, rs,
                                          gwbf + (size_t)l*32768, gb + l*128,
                                          lng + l*128, lnb + l*128, h, hbf);
  }
  k_pool<<<NN/8, 128, 0, stream>>>(h, batch, sums, counts);
  k_final<<<NG, 128, 0, stream>>>(sums, counts, p1W, p1b, l1g, l1b,
                                  p2W, p2b, l2g, l2b, (float*)d_out);
}

// Round 4
// 529.862 us; speedup vs baseline: 3.8559x; 1.0473x over previous
//
#include <hip/hip_runtime.h>

#define NN 10000
#define NNP 10048   // padded to 628*16
#define NE 160000
#define NG 64
#define HID 128
#define NL 3

#define TEB 128    // edges per block in k_edge
#define TNB 16     // nodes per block in k_update

typedef float floatx4 __attribute__((ext_vector_type(4)));
typedef short bf16x8 __attribute__((ext_vector_type(8)));

__device__ __forceinline__ float fsig(float x){ return 1.f/(1.f+__expf(-x)); }

__device__ __forceinline__ short f2bf(float f){
  union { float f; unsigned u; } a; a.f = f;
  unsigned r = a.u + 0x7FFF + ((a.u >> 16) & 1);
  return (short)(r >> 16);
}

// XOR-swizzled element offset into a [128][256] bf16 tile (16B-chunk swizzle).
// Stride 256 bf16 = 512B; swizzle pc = c ^ (row&7) gives conflict-free (<=2-way)
// access for both row-major staging writes and MFMA B-fragment reads.
__device__ __forceinline__ int swz(int row, int chunk){
  return row*256 + ((chunk ^ (row & 7)) << 3);
}

// ---------------- prep: repack weights into MFMA A-fragment layout (bf16) ----------------
// frag layout: idx = ((((mb*8 + s)*4 + quad)*16 + col)*8 + t
//   value = W[out = mb*16+col][k = s*32 + quad*8 + t]
// so a wave's A-load is base + lane*16B (fully coalesced).
__global__ void k_prep(const float* __restrict__ m1, const float* __restrict__ m2,
                       const float* __restrict__ mg,
                       short* __restrict__ w1f, float* __restrict__ w256,
                       short* __restrict__ w2f, short* __restrict__ gwf){
  int i = blockIdx.x*256 + threadIdx.x;
  const int A = NL*65536;
  const int B = A + NL*32768;
  const int C = B + NL*32768;
  const int D = C + NL*256;
  if (i < A){
    int l = i>>16, j = i&65535;
    int t=j&7, col=(j>>3)&15, quad=(j>>7)&3, s=(j>>9)&7, mb=(j>>12)&15;
    w1f[i] = f2bf(m1[l*65792 + (mb*16+col)*257 + s*32 + quad*8 + t]);
  } else if (i < B){
    int j = i-A; int l = j>>15; j &= 32767;
    int t=j&7, col=(j>>3)&15, quad=(j>>7)&3, s=(j>>9)&7, mb=(j>>12)&7;
    w2f[(l<<15)+j] = f2bf(m2[l*32768 + (mb*16+col)*256 + s*32 + quad*8 + t]);
  } else if (i < C){
    int j = i-B; int l = j>>15; j &= 32767;
    int t=j&7, col=(j>>3)&15, quad=(j>>7)&3, s=(j>>9)&7, mb=(j>>12)&7;
    gwf[(l<<15)+j] = f2bf(mg[l*32768 + (mb*16+col)*256 + s*32 + quad*8 + t]);
  } else if (i < D){
    int j = i-C; int l = j>>8, o = j&255;
    w256[j] = m1[l*65792 + o*257 + 256];
  }
}

// ---------------- CSR build ----------------
__global__ void k_hist(const int* __restrict__ ei, int* __restrict__ deg){
  int e = blockIdx.x*256 + threadIdx.x;
  atomicAdd(&deg[ei[NE + e]], 1);
}

__global__ void k_scan(const int* __restrict__ deg, int* __restrict__ rs){
  __shared__ int ps[257];
  const int t = threadIdx.x;
  const int base = t*40;
  int s = 0;
  for (int i=0;i<40;i++){ int idx=base+i; if (idx<NNP) s += deg[idx]; }
  ps[t+1] = s;
  __syncthreads();
  if (t==0){ ps[0]=0; for (int i=1;i<=256;i++) ps[i]+=ps[i-1]; }
  __syncthreads();
  int run = ps[t];
  for (int i=0;i<40;i++){ int idx=base+i; if (idx<NNP){ rs[idx]=run; run+=deg[idx]; } }
  if (t==255) rs[NNP] = ps[256];
}

__global__ void k_rank(const int* __restrict__ ei, const float* __restrict__ ea,
                       const int* __restrict__ rs, int* __restrict__ cursor,
                       int* __restrict__ esrc, int* __restrict__ edst,
                       float* __restrict__ eas){
  int e = blockIdx.x*256 + threadIdx.x;
  int d = ei[NE + e];
  int pos = rs[d] + atomicAdd(&cursor[d], 1);
  esrc[pos] = ei[e];
  edst[pos] = d;
  eas[pos]  = ea[e];
}

// ---------------- node embedding: h = silu(LN(x @ embW^T + b)), + bf16 copy ----------------
__global__ void k_embed(const float* __restrict__ x, const float* __restrict__ W,
                        const float* __restrict__ b, const float* __restrict__ g,
                        const float* __restrict__ bb, float* __restrict__ h,
                        short* __restrict__ hbf){
  const int n = blockIdx.x, c = threadIdx.x;
  if (n >= NN){ h[(size_t)n*HID + c] = 0.f; hbf[(size_t)n*HID + c] = 0; return; }
  __shared__ float red[4];
  float x0 = x[n*3+0], x1 = x[n*3+1], x2 = x[n*3+2];
  float v = W[c*3+0]*x0 + W[c*3+1]*x1 + W[c*3+2]*x2 + b[c];
  float s = v, s2 = v*v;
#pragma unroll
  for (int m=1;m<64;m<<=1){ s += __shfl_xor(s,m,64); s2 += __shfl_xor(s2,m,64); }
  if ((c & 63) == 0){ red[(c>>6)*2] = s; red[(c>>6)*2+1] = s2; }
  __syncthreads();
  float S = red[0]+red[2], S2 = red[1]+red[3];
  float mean = S*(1.f/128.f);
  float var = S2*(1.f/128.f) - mean*mean;
  float y = (v-mean)*rsqrtf(var+1e-5f)*g[c] + bb[c];
  float o = y * fsig(y);
  h[(size_t)n*HID + c] = o;
  hbf[(size_t)n*HID + c] = f2bf(o);
}

// ---------------- edge MLP (bf16 MFMA), sorted edges, fp16 msg store ----------------
// wave wv: ehalf = wv&1 -> edges [ehalf*64, +64), ohalf = wv>>1 -> out half.
// GEMM1: mt=8 (128 outs/wave), nt=4 (64 edges/wave). GEMM2: mt=4 (64 outs/wave).
__global__ __launch_bounds__(256,2) void k_edge(
    const short* __restrict__ hbf,
    const int* __restrict__ esrc, const int* __restrict__ edst,
    const float* __restrict__ eas,
    const short* __restrict__ w1f, const float* __restrict__ w256,
    const float* __restrict__ b1,
    const short* __restrict__ w2f, const float* __restrict__ b2,
    unsigned short* __restrict__ msg)
{
  __shared__ __align__(16) short Zs[TEB*256];   // 64 KB, swizzled; Z then M1
  const int tid = threadIdx.x;
  const int wv = tid >> 6, lane = tid & 63;
  const int col = lane & 15, quad = lane >> 4;
  const int ehalf = wv & 1, ohalf = wv >> 1;
  const int e0 = blockIdx.x * TEB;

  { // stage Z: 2 threads per edge; dst row -> chunks 0..15, src row -> 16..31
    int e = tid >> 1, half = tid & 1;
    int node = half ? esrc[e0+e] : edst[e0+e];
    const short* hr = hbf + (size_t)node * HID;
#pragma unroll
    for (int i=0;i<16;i++)
      *(bf16x8*)(&Zs[swz(e, half*16 + i)]) = *(const bf16x8*)(hr + i*8);
  }
  float eav[4];
#pragma unroll
  for (int nt=0; nt<4; nt++) eav[nt] = eas[e0 + ehalf*64 + nt*16 + col];
  __syncthreads();

  // ---- GEMM1 ----
  floatx4 acc[8][4];
#pragma unroll
  for (int i=0;i<8;i++)
#pragma unroll
    for (int j=0;j<4;j++) acc[i][j] = (floatx4)(0.f);

  const short* wb1 = w1f + ohalf*32768 + quad*128 + col*8;
#pragma unroll
  for (int s=0; s<8; s++){
    bf16x8 bfrag[4];
#pragma unroll
    for (int nt=0; nt<4; nt++)
      bfrag[nt] = *(const bf16x8*)(&Zs[swz(ehalf*64 + nt*16 + col, s*4 + quad)]);
#pragma unroll
    for (int mt=0; mt<8; mt++){
      bf16x8 afrag = *(const bf16x8*)(wb1 + mt*4096 + s*512);
#pragma unroll
      for (int nt=0; nt<4; nt++)
        acc[mt][nt] = __builtin_amdgcn_mfma_f32_16x16x32_bf16(afrag, bfrag[nt], acc[mt][nt], 0,0,0);
    }
  }
  __syncthreads();   // all waves done reading Z

  // epilogue: bias + ea rank-1 + silu -> M1 (bf16, back into Zs)
#pragma unroll
  for (int mt=0; mt<8; mt++){
    int outb = ohalf*128 + mt*16 + quad*4;
    float4 b1v   = *(const float4*)(b1 + outb);
    float4 w256v = *(const float4*)(w256 + outb);
    float bb[4] = {b1v.x, b1v.y, b1v.z, b1v.w};
    float ww[4] = {w256v.x, w256v.y, w256v.z, w256v.w};
#pragma unroll
    for (int nt=0; nt<4; nt++){
      int erow = ehalf*64 + nt*16 + col;
      union { short s[4]; int2 v; } pk;
#pragma unroll
      for (int r=0;r<4;r++){
        float v = acc[mt][nt][r] + eav[nt]*ww[r] + bb[r];
        pk.s[r] = f2bf(v * fsig(v));
      }
      *(int2*)(&Zs[swz(erow, outb>>3) + (outb&7)]) = pk.v;
    }
  }
  __syncthreads();

  // ---- GEMM2 ----
  floatx4 acc2[4][4];
#pragma unroll
  for (int i=0;i<4;i++)
#pragma unroll
    for (int j=0;j<4;j++) acc2[i][j] = (floatx4)(0.f);

  const short* wb2 = w2f + ohalf*16384 + quad*128 + col*8;
#pragma unroll
  for (int s=0; s<8; s++){
    bf16x8 bfrag[4];
#pragma unroll
    for (int nt=0; nt<4; nt++)
      bfrag[nt] = *(const bf16x8*)(&Zs[swz(ehalf*64 + nt*16 + col, s*4 + quad)]);
#pragma unroll
    for (int mt=0; mt<4; mt++){
      bf16x8 afrag = *(const bf16x8*)(wb2 + mt*4096 + s*512);
#pragma unroll
      for (int nt=0; nt<4; nt++)
        acc2[mt][nt] = __builtin_amdgcn_mfma_f32_16x16x32_bf16(afrag, bfrag[nt], acc2[mt][nt], 0,0,0);
    }
  }

  // store msg (fp16) at sorted row
#pragma unroll
  for (int mt=0; mt<4; mt++){
    int outb = ohalf*64 + mt*16 + quad*4;
    float4 b2v = *(const float4*)(b2 + outb);
    float bb[4] = {b2v.x, b2v.y, b2v.z, b2v.w};
#pragma unroll
    for (int nt=0; nt<4; nt++){
      int erow = ehalf*64 + nt*16 + col;
      union { _Float16 hx[4]; uint2 u; } pk;
#pragma unroll
      for (int r=0;r<4;r++)
        pk.hx[r] = (_Float16)(acc2[mt][nt][r] + bb[r]);
      *(uint2*)(msg + (size_t)(e0 + erow)*HID + outb) = pk.u;
    }
  }
}

// ---------------- fused aggregation + gate MFMA + residual + LN ----------------
__global__ __launch_bounds__(256) void k_update(
    const short* __restrict__ hbf, const float* __restrict__ h,
    const unsigned short* __restrict__ msg, const int* __restrict__ rs,
    const short* __restrict__ gwf, const float* __restrict__ gb,
    const float* __restrict__ lng, const float* __restrict__ lnb,
    float* __restrict__ hout, short* __restrict__ hbfout)
{
  __shared__ __align__(16) short HB[TNB][264];  // [node][k]: k<128 h, k>=128 aggr (bf16)
  __shared__ float Agg[TNB][132];               // fp32 aggregation
  __shared__ float reds[4][TNB], reds2[4][TNB];
  const int tid = threadIdx.x;
  const int wv = tid >> 6, lane = tid & 63;
  const int col = lane & 15, quad = lane >> 4;
  const int n0 = blockIdx.x * TNB;

  { // stage h rows (bf16)
    int n = tid >> 4, c = tid & 15;
    *(bf16x8*)(&HB[n][c*8]) = *(const bf16x8*)(hbf + (size_t)(n0+n)*HID + c*8);
  }
  { // aggregate msg rows (CSR) -> Agg fp32 + HB bf16
    int n = tid >> 4, q = tid & 15;
    float a[8];
#pragma unroll
    for (int j=0;j<8;j++) a[j] = 0.f;
    int rb = rs[n0+n], re = rs[n0+n+1];
    for (int r=rb; r<re; r++){
      union { uint4 u; _Float16 hx[8]; } ld;
      ld.u = *(const uint4*)(msg + (size_t)r*HID + q*8);
#pragma unroll
      for (int j=0;j<8;j++) a[j] += (float)ld.hx[j];
    }
    *(float4*)(&Agg[n][q*8])   = make_float4(a[0],a[1],a[2],a[3]);
    *(float4*)(&Agg[n][q*8+4]) = make_float4(a[4],a[5],a[6],a[7]);
    union { short s[8]; bf16x8 v; } pk;
#pragma unroll
    for (int j=0;j<8;j++) pk.s[j] = f2bf(a[j]);
    *(bf16x8*)(&HB[n][128 + q*8]) = pk.v;
  }
  __syncthreads();

  // gate GEMM: wave wv -> outs [wv*32, +32), nodes = col
  floatx4 acc[2];
  acc[0] = (floatx4)(0.f); acc[1] = (floatx4)(0.f);
  const short* wb = gwf + quad*128 + col*8;
#pragma unroll
  for (int s=0; s<8; s++){
    bf16x8 bfrag = *(const bf16x8*)(&HB[col][s*32 + quad*8]);
#pragma unroll
    for (int mt=0; mt<2; mt++){
      bf16x8 afrag = *(const bf16x8*)(wb + (wv*2+mt)*4096 + s*512);
      acc[mt] = __builtin_amdgcn_mfma_f32_16x16x32_bf16(afrag, bfrag, acc[mt], 0,0,0);
    }
  }

  // epilogue: gate, residual; LN across the 128 outs of node (n0+col)
  float vv[2][4], ss=0.f, ss2=0.f;
#pragma unroll
  for (int mt=0; mt<2; mt++){
    int outb = (wv*2+mt)*16 + quad*4;
    float4 gbv = *(const float4*)(gb + outb);
    float4 hv  = *(const float4*)(h + (size_t)(n0+col)*HID + outb);
    float4 av  = *(const float4*)(&Agg[col][outb]);
    float gg[4] = {gbv.x, gbv.y, gbv.z, gbv.w};
    float hh[4] = {hv.x, hv.y, hv.z, hv.w};
    float aa[4] = {av.x, av.y, av.z, av.w};
#pragma unroll
    for (int r=0;r<4;r++){
      float gate = fsig(acc[mt][r] + gg[r]);
      float v = hh[r] + gate*aa[r] + (1.f-gate)*hh[r];
      vv[mt][r] = v; ss += v; ss2 += v*v;
    }
  }
  ss  += __shfl_xor(ss, 16, 64);  ss  += __shfl_xor(ss, 32, 64);
  ss2 += __shfl_xor(ss2, 16, 64); ss2 += __shfl_xor(ss2, 32, 64);
  if (quad == 0){ reds[wv][col] = ss; reds2[wv][col] = ss2; }
  __syncthreads();

  float S  = reds[0][col]+reds[1][col]+reds[2][col]+reds[3][col];
  float S2 = reds2[0][col]+reds2[1][col]+reds2[2][col]+reds2[3][col];
  float mean = S*(1.f/128.f);
  float var  = S2*(1.f/128.f) - mean*mean;
  float rsq  = rsqrtf(var + 1e-5f);
  int node = n0 + col;
#pragma unroll
  for (int mt=0; mt<2; mt++){
    int outb = (wv*2+mt)*16 + quad*4;
    float4 gv = *(const float4*)(lng + outb);
    float4 bv = *(const float4*)(lnb + outb);
    float gvl[4] = {gv.x, gv.y, gv.z, gv.w};
    float bvl[4] = {bv.x, bv.y, bv.z, bv.w};
    float4 outv;
    float* ov = (float*)&outv;
    union { short sh[4]; int2 v; } pk;
#pragma unroll
    for (int r=0;r<4;r++){
      float o = (vv[mt][r]-mean)*rsq*gvl[r] + bvl[r];
      ov[r] = o; pk.sh[r] = f2bf(o);
    }
    *(float4*)(hout + (size_t)node*HID + outb) = outv;
    *(int2*)(hbfout + (size_t)node*HID + outb) = pk.v;
  }
}

// ---------------- pooling: segmented sums (batch is sorted) ----------------
__global__ void k_pool(const float* __restrict__ h, const int* __restrict__ batch,
                       float* __restrict__ sums, float* __restrict__ counts){
  const int c = threadIdx.x;
  const int n0 = blockIdx.x * 8;
  int cur = batch[n0];
  float local = 0.f, cnt = 0.f;
  for (int i=0;i<8;i++){
    int n = n0 + i;
    int g = batch[n];
    if (g != cur){
      atomicAdd(&sums[cur*HID + c], local);
      if (c==0) atomicAdd(&counts[cur], cnt);
      local = 0.f; cnt = 0.f; cur = g;
    }
    local += h[(size_t)n*HID + c];
    cnt += 1.f;
  }
  atomicAdd(&sums[cur*HID + c], local);
  if (c==0) atomicAdd(&counts[cur], cnt);
}

// ---------------- x_global + projector ----------------
__global__ void k_final(const float* __restrict__ sums, const float* __restrict__ counts,
    const float* __restrict__ p1W, const float* __restrict__ p1b,
    const float* __restrict__ l1g, const float* __restrict__ l1b,
    const float* __restrict__ p2W, const float* __restrict__ p2b,
    const float* __restrict__ l2g, const float* __restrict__ l2b,
    float* __restrict__ out){
  const int g = blockIdx.x, c = threadIdx.x;
  __shared__ float xg[HID], p[HID], red[4];
  float cnt = counts[g];
  float s = sums[g*HID + c];
  float xgv = s * (1.f/fmaxf(cnt,1.f) + 1.f/(cnt + 1e-6f));
  out[NG*64 + g*HID + c] = xgv;
  xg[c] = xgv;
  __syncthreads();
  float v = p1b[c];
  for (int k=0;k<HID;k++) v += xg[k]*p1W[c*HID + k];
  float sv=v, sv2=v*v;
#pragma unroll
  for (int m=1;m<64;m<<=1){ sv+=__shfl_xor(sv,m,64); sv2+=__shfl_xor(sv2,m,64); }
  if ((c&63)==0){ red[(c>>6)*2]=sv; red[(c>>6)*2+1]=sv2; }
  __syncthreads();
  float S=red[0]+red[2], S2=red[1]+red[3];
  float mean=S*(1.f/128.f), var=S2*(1.f/128.f)-mean*mean;
  float y=(v-mean)*rsqrtf(var+1e-5f)*l1g[c]+l1b[c];
  p[c] = y*fsig(y);
  __syncthreads();
  if (c < 64){
    float z = p2b[c];
    for (int k=0;k<HID;k++) z += p[k]*p2W[c*HID + k];
    float t=z, t2=z*z;
#pragma unroll
    for (int m=1;m<64;m<<=1){ t+=__shfl_xor(t,m,64); t2+=__shfl_xor(t2,m,64); }
    float mn=t*(1.f/64.f), vr=t2*(1.f/64.f)-mn*mn;
    out[g*64 + c] = (z-mn)*rsqrtf(vr+1e-5f)*l2g[c]+l2b[c];
  }
}

extern "C" void kernel_launch(void* const* d_in, const int* in_sizes, int n_in,
                              void* d_out, int out_size, void* d_ws, size_t ws_size,
                              hipStream_t stream){
  const float* x     = (const float*)d_in[0];
  const float* ea    = (const float*)d_in[1];
  const int*   ei    = (const int*)  d_in[2];
  const int*   batch = (const int*)  d_in[3];
  const float* embW  = (const float*)d_in[4];
  const float* embB  = (const float*)d_in[5];
  const float* embG  = (const float*)d_in[6];
  const float* embBe = (const float*)d_in[7];
  const float* m1W   = (const float*)d_in[8];
  const float* m1b   = (const float*)d_in[9];
  const float* m2W   = (const float*)d_in[10];
  const float* m2b   = (const float*)d_in[11];
  const float* gW    = (const float*)d_in[12];
  const float* gb    = (const float*)d_in[13];
  const float* lng   = (const float*)d_in[14];
  const float* lnb   = (const float*)d_in[15];
  const float* p1W   = (const float*)d_in[16];
  const float* p1b   = (const float*)d_in[17];
  const float* l1g   = (const float*)d_in[18];
  const float* l1b   = (const float*)d_in[19];
  const float* p2W   = (const float*)d_in[20];
  const float* p2b   = (const float*)d_in[21];
  const float* l2g   = (const float*)d_in[22];
  const float* l2b   = (const float*)d_in[23];

  char* p = (char*)d_ws;
  auto alloc = [&](size_t bytes){ char* r = p; p += (bytes + 255) & ~(size_t)255; return r; };
  float* h    = (float*) alloc((size_t)NNP*HID*4);
  short* hbf  = (short*) alloc((size_t)NNP*HID*2);
  unsigned short* msg = (unsigned short*) alloc((size_t)NE*HID*2);
  short* w1f  = (short*) alloc((size_t)NL*65536*2);
  short* w2f  = (short*) alloc((size_t)NL*32768*2);
  short* gwf  = (short*) alloc((size_t)NL*32768*2);
  float* w256 = (float*) alloc((size_t)NL*256*4);
  int* deg    = (int*)   alloc((size_t)NNP*4);
  int* cursor = (int*)   alloc((size_t)NNP*4);
  int* rs     = (int*)   alloc((size_t)(NNP+1)*4);
  int* esrc   = (int*)   alloc((size_t)NE*4);
  int* edst   = (int*)   alloc((size_t)NE*4);
  float* eas  = (float*) alloc((size_t)NE*4);
  float* sums = (float*) alloc((size_t)NG*HID*4);
  float* counts=(float*) alloc((size_t)NG*4);

  hipMemsetAsync(deg, 0, (size_t)NNP*4, stream);
  hipMemsetAsync(cursor, 0, (size_t)NNP*4, stream);
  hipMemsetAsync(sums, 0, (size_t)NG*HID*4, stream);
  hipMemsetAsync(counts, 0, (size_t)NG*4, stream);

  const int PT = NL*65536 + 2*NL*32768 + NL*256;
  k_prep<<<(PT+255)/256, 256, 0, stream>>>(m1W, m2W, gW, w1f, w256, w2f, gwf);
  k_embed<<<NNP, 128, 0, stream>>>(x, embW, embB, embG, embBe, h, hbf);
  k_hist<<<NE/256, 256, 0, stream>>>(ei, deg);
  k_scan<<<1, 256, 0, stream>>>(deg, rs);
  k_rank<<<NE/256, 256, 0, stream>>>(ei, ea, rs, cursor, esrc, edst, eas);

  for (int l=0; l<NL; l++){
    k_edge<<<NE/TEB, 256, 0, stream>>>(hbf, esrc, edst, eas,
                                       w1f + (size_t)l*65536, w256 + l*256, m1b + l*256,
                                       w2f + (size_t)l*32768, m2b + l*128, msg);
    k_update<<<NNP/TNB, 256, 0, stream>>>(hbf, h, msg, rs,
                                          gwf + (size_t)l*32768, gb + l*128,
                                          lng + l*128, lnb + l*128, h, hbf);
  }
  k_pool<<<NN/8, 128, 0, stream>>>(h, batch, sums, counts);
  k_final<<<NG, 128, 0, stream>>>(sums, counts, p1W, p1b, l1g, l1b,
                                  p2W, p2b, l2g, l2b, (float*)d_out);
}

// Round 6
// 416.407 us; speedup vs baseline: 4.9065x; 1.2725x over previous
//
#include <hip/hip_runtime.h>

#define NN 10000
#define NNP 10048
#define NE 160000
#define NG 64
#define HID 128
#define NL 3

typedef float floatx4 __attribute__((ext_vector_type(4)));
typedef _Float16 f16x8 __attribute__((ext_vector_type(8)));
typedef __fp16 f16x2 __attribute__((ext_vector_type(2)));   // return type of cvt_pkrtz

__device__ __forceinline__ float fsig(float x){
  return __builtin_amdgcn_rcpf(1.f + __expf(-x));
}

// ---------------- prep: repack weights into fp16 MFMA A-fragment layouts ----------------
// wnf: [l][512 out][128 k]  rows 0..255 = W1[:,0:128] (dst part), 256..511 = W1[:,128:256] (src)
//   frag idx = (((mb*4+s)*4+quad)*16+col)*8+t ; out=mb*16+col, k=s*32+quad*8+t
// w2f/gwf: [l][128 out][256 k], frag idx = (((mb*8+s)*4+quad)*16+col)*8+t
__global__ void k_prep(const float* __restrict__ m1, const float* __restrict__ m2,
                       const float* __restrict__ mg, const float* __restrict__ m1b,
                       _Float16* __restrict__ wnf, _Float16* __restrict__ w2f,
                       _Float16* __restrict__ gwf,
                       float* __restrict__ w256, float* __restrict__ biasUV){
  int i = blockIdx.x*256 + threadIdx.x;
  const int A = NL*65536;
  const int B = A + NL*32768;
  const int C = B + NL*32768;
  const int D = C + NL*256;
  const int E = D + NL*512;
  if (i < A){
    int l = i>>16, j = i&65535;
    int t=j&7, col=(j>>3)&15, quad=(j>>7)&3, s=(j>>9)&3, mb=(j>>11)&31;
    int o = mb*16+col, k = s*32+quad*8+t;
    float v = (o < 256) ? m1[l*65792 + o*257 + k] : m1[l*65792 + (o-256)*257 + 128 + k];
    wnf[i] = (_Float16)v;
  } else if (i < B){
    int j = i-A; int l = j>>15; j &= 32767;
    int t=j&7, col=(j>>3)&15, quad=(j>>7)&3, s=(j>>9)&7, mb=(j>>12)&7;
    w2f[(l<<15)+j] = (_Float16)m2[l*32768 + (mb*16+col)*256 + s*32+quad*8+t];
  } else if (i < C){
    int j = i-B; int l = j>>15; j &= 32767;
    int t=j&7, col=(j>>3)&15, quad=(j>>7)&3, s=(j>>9)&7, mb=(j>>12)&7;
    gwf[(l<<15)+j] = (_Float16)mg[l*32768 + (mb*16+col)*256 + s*32+quad*8+t];
  } else if (i < D){
    int j = i-C; int l = j>>8, o = j&255;
    w256[j] = m1[l*65792 + o*257 + 256];
  } else if (i < E){
    int j = i-D; int o = j&511;
    biasUV[j] = (o < 256) ? m1b[(j>>9)*256 + o] : 0.f;
  }
}

// ---------------- CSR build ----------------
__global__ void k_hist(const int* __restrict__ ei, int* __restrict__ deg){
  int e = blockIdx.x*256 + threadIdx.x;
  atomicAdd(&deg[ei[NE + e]], 1);
}

__global__ void k_scan(const int* __restrict__ deg, int* __restrict__ rs){
  __shared__ int ps[257];
  const int t = threadIdx.x;
  const int base = t*40;
  int s = 0;
  for (int i=0;i<40;i++){ int idx=base+i; if (idx<NNP) s += deg[idx]; }
  ps[t+1] = s;
  __syncthreads();
  if (t==0){ ps[0]=0; for (int i=1;i<=256;i++) ps[i]+=ps[i-1]; }
  __syncthreads();
  int run = ps[t];
  for (int i=0;i<40;i++){ int idx=base+i; if (idx<NNP){ rs[idx]=run; run+=deg[idx]; } }
  if (t==255) rs[NNP] = ps[256];
}

__global__ void k_rank(const int* __restrict__ ei, const float* __restrict__ ea,
                       const int* __restrict__ rs, int* __restrict__ cursor,
                       int* __restrict__ esrc, int* __restrict__ edst,
                       float* __restrict__ eas){
  int e = blockIdx.x*256 + threadIdx.x;
  int d = ei[NE + e];
  int pos = rs[d] + atomicAdd(&cursor[d], 1);
  esrc[pos] = ei[e];
  edst[pos] = d;
  eas[pos]  = ea[e];
}

// ---------------- node embedding (2 nodes per 256-thr block) ----------------
__global__ void k_embed(const float* __restrict__ x, const float* __restrict__ W,
                        const float* __restrict__ b, const float* __restrict__ g,
                        const float* __restrict__ bb, float* __restrict__ h,
                        _Float16* __restrict__ hf){
  const int tid = threadIdx.x;
  const int nn = tid>>7, c = tid&127;
  const int n = blockIdx.x*2 + nn;
  __shared__ float red[2][2][2];
  float x0=0.f, x1=0.f, x2=0.f;
  if (n < NN){ x0 = x[n*3]; x1 = x[n*3+1]; x2 = x[n*3+2]; }
  float v = W[c*3]*x0 + W[c*3+1]*x1 + W[c*3+2]*x2 + b[c];
  float s = v, s2 = v*v;
#pragma unroll
  for (int m=1;m<64;m<<=1){ s += __shfl_xor(s,m,64); s2 += __shfl_xor(s2,m,64); }
  if ((c & 63) == 0){ red[nn][c>>6][0] = s; red[nn][c>>6][1] = s2; }
  __syncthreads();
  float S  = red[nn][0][0]+red[nn][1][0];
  float S2 = red[nn][0][1]+red[nn][1][1];
  float mean = S*(1.f/128.f);
  float var = S2*(1.f/128.f) - mean*mean;
  float y = (v-mean)*rsqrtf(var+1e-5f)*g[c] + bb[c];
  float o = y * fsig(y);
  h[(size_t)n*HID + c] = o;
  hf[(size_t)n*HID + c] = (_Float16)o;
}

// ---------------- node GEMM: UV[node][512] = [W1a.h + b1 ; W1b.h] (fp16) ----------------
__global__ __launch_bounds__(256) void k_nodeUV(
    const _Float16* __restrict__ hf,
    const _Float16* __restrict__ wnf, const float* __restrict__ biasUV,
    _Float16* __restrict__ UV)
{
  const int tid = threadIdx.x;
  const int wv = tid>>6, lane = tid&63;
  const int col = lane&15, quad = lane>>4;
  const int node = blockIdx.x*16 + col;

  f16x8 bfrag[4];
#pragma unroll
  for (int s=0;s<4;s++)
    bfrag[s] = *(const f16x8*)(hf + (size_t)node*HID + s*32 + quad*8);

  floatx4 acc[8];
#pragma unroll
  for (int i=0;i<8;i++) acc[i] = (floatx4)(0.f);

  const _Float16* wb = wnf + quad*128 + col*8;
#pragma unroll
  for (int s=0;s<4;s++)
#pragma unroll
    for (int mt=0;mt<8;mt++){
      f16x8 a = *(const f16x8*)(wb + (size_t)((wv*8+mt)*4+s)*512);
      acc[mt] = __builtin_amdgcn_mfma_f32_16x16x32_f16(a, bfrag[s], acc[mt], 0,0,0);
    }

#pragma unroll
  for (int mt=0;mt<8;mt++){
    int o0 = wv*128 + mt*16 + quad*4;
    float4 bv = *(const float4*)(biasUV + o0);
    union { f16x2 h2[2]; uint2 u; } pk;
    pk.h2[0] = __builtin_amdgcn_cvt_pkrtz(acc[mt][0]+bv.x, acc[mt][1]+bv.y);
    pk.h2[1] = __builtin_amdgcn_cvt_pkrtz(acc[mt][2]+bv.z, acc[mt][3]+bv.w);
    *(uint2*)(UV + (size_t)node*512 + o0) = pk.u;
  }
}

// ---------------- edge kernel: gather U+V, silu, GEMM2 (fp16 MFMA), msg store ----------------
// No LDS, no barriers. Wave = 32 edges (nt=2), all 128 outs (mt=8).
__global__ __launch_bounds__(256,3) void k_edge(
    const _Float16* __restrict__ UV,
    const int* __restrict__ esrc, const int* __restrict__ edst,
    const float* __restrict__ eas,
    const float* __restrict__ w256, const _Float16* __restrict__ w2f,
    const float* __restrict__ b2,
    _Float16* __restrict__ msg)
{
  const int tid = threadIdx.x;
  const int wv = tid>>6, lane = tid&63;
  const int col = lane&15, quad = lane>>4;
  const int e0 = (blockIdx.x*4 + wv)*32;

  int dn[2], sn[2]; float eav[2];
#pragma unroll
  for (int nt=0;nt<2;nt++){
    int e = e0 + nt*16 + col;
    dn[nt] = edst[e]; sn[nt] = esrc[e]; eav[nt] = eas[e];
  }
  const _Float16* up[2], *vp[2];
#pragma unroll
  for (int nt=0;nt<2;nt++){
    up[nt] = UV + (size_t)dn[nt]*512 + quad*8;
    vp[nt] = UV + (size_t)sn[nt]*512 + 256 + quad*8;
  }

  floatx4 acc[8][2];
#pragma unroll
  for (int i=0;i<8;i++){ acc[i][0] = (floatx4)(0.f); acc[i][1] = (floatx4)(0.f); }

  const _Float16* wA = w2f + quad*128 + col*8;

#pragma unroll 2
  for (int s=0;s<8;s++){
    float4 wc0 = *(const float4*)(w256 + s*32 + quad*8);
    float4 wc1 = *(const float4*)(w256 + s*32 + quad*8 + 4);
    float wc[8] = {wc0.x,wc0.y,wc0.z,wc0.w, wc1.x,wc1.y,wc1.z,wc1.w};
    f16x8 b[2];
#pragma unroll
    for (int nt=0;nt<2;nt++){
      f16x8 u = *(const f16x8*)(up[nt] + s*32);
      f16x8 v = *(const f16x8*)(vp[nt] + s*32);
      float m[8];
#pragma unroll
      for (int t=0;t<8;t++){
        float f = (float)u[t] + (float)v[t] + eav[nt]*wc[t];
        m[t] = f * fsig(f);
      }
      union { f16x2 h2[4]; f16x8 v8; } pb;
      pb.h2[0] = __builtin_amdgcn_cvt_pkrtz(m[0],m[1]);
      pb.h2[1] = __builtin_amdgcn_cvt_pkrtz(m[2],m[3]);
      pb.h2[2] = __builtin_amdgcn_cvt_pkrtz(m[4],m[5]);
      pb.h2[3] = __builtin_amdgcn_cvt_pkrtz(m[6],m[7]);
      b[nt] = pb.v8;
    }
#pragma unroll
    for (int mt=0;mt<8;mt++){
      f16x8 a = *(const f16x8*)(wA + (size_t)(mt*8+s)*512);
      acc[mt][0] = __builtin_amdgcn_mfma_f32_16x16x32_f16(a, b[0], acc[mt][0], 0,0,0);
      acc[mt][1] = __builtin_amdgcn_mfma_f32_16x16x32_f16(a, b[1], acc[mt][1], 0,0,0);
    }
  }

#pragma unroll
  for (int mt=0;mt<8;mt++){
    int outb = mt*16 + quad*4;
    float4 b2v = *(const float4*)(b2 + outb);
#pragma unroll
    for (int nt=0;nt<2;nt++){
      int e = e0 + nt*16 + col;
      union { f16x2 h2[2]; uint2 u; } pk;
      pk.h2[0] = __builtin_amdgcn_cvt_pkrtz(acc[mt][nt][0]+b2v.x, acc[mt][nt][1]+b2v.y);
      pk.h2[1] = __builtin_amdgcn_cvt_pkrtz(acc[mt][nt][2]+b2v.z, acc[mt][nt][3]+b2v.w);
      *(uint2*)(msg + (size_t)e*HID + outb) = pk.u;
    }
  }
}

// ---------------- fused aggregation + gate MFMA + residual + LN (512 thr, 16 nodes) ----------------
__global__ __launch_bounds__(512) void k_update(
    const _Float16* __restrict__ hf, const float* __restrict__ h,
    const _Float16* __restrict__ msg, const int* __restrict__ rs,
    const _Float16* __restrict__ gwf, const float* __restrict__ gb,
    const float* __restrict__ lng, const float* __restrict__ lnb,
    float* __restrict__ hout, _Float16* __restrict__ hfout)
{
  __shared__ _Float16 HB[16][264];   // [node][k] fp16: k<128 h, k>=128 aggr
  __shared__ float Agg[16][132];
  __shared__ float reds[8][16], reds2[8][16];
  const int tid = threadIdx.x;
  const int wv = tid>>6, lane = tid&63;
  const int col = lane&15, quad = lane>>4;
  const int n0 = blockIdx.x*16;

  { // stage h rows (fp16), 32 threads per node
    int n = tid>>5, c = tid&31;
    *(uint2*)(&HB[n][c*4]) = *(const uint2*)(hf + (size_t)(n0+n)*HID + c*4);
  }
  { // aggregate CSR msg rows, 2-way row split per node
    int n = tid>>5, rh = (tid>>4)&1, q = tid&15;
    float a[8];
#pragma unroll
    for (int j=0;j<8;j++) a[j] = 0.f;
    int rb = rs[n0+n], re = rs[n0+n+1];
    for (int r=rb+rh; r<re; r+=2){
      union { uint4 u; _Float16 hx[8]; } ld;
      ld.u = *(const uint4*)(msg + (size_t)r*HID + q*8);
#pragma unroll
      for (int j=0;j<8;j++) a[j] += (float)ld.hx[j];
    }
#pragma unroll
    for (int j=0;j<8;j++) a[j] += __shfl_xor(a[j], 16, 64);
    if (rh == 0){
      *(float4*)(&Agg[n][q*8])   = make_float4(a[0],a[1],a[2],a[3]);
      *(float4*)(&Agg[n][q*8+4]) = make_float4(a[4],a[5],a[6],a[7]);
      union { f16x2 h2[4]; uint4 u; } pk;
      pk.h2[0] = __builtin_amdgcn_cvt_pkrtz(a[0],a[1]);
      pk.h2[1] = __builtin_amdgcn_cvt_pkrtz(a[2],a[3]);
      pk.h2[2] = __builtin_amdgcn_cvt_pkrtz(a[4],a[5]);
      pk.h2[3] = __builtin_amdgcn_cvt_pkrtz(a[6],a[7]);
      *(uint4*)(&HB[n][128 + q*8]) = pk.u;
    }
  }
  __syncthreads();

  // gate GEMM: wave wv -> outs [wv*16, +16), nodes = col
  floatx4 acc = (floatx4)(0.f);
  const _Float16* wb = gwf + quad*128 + col*8;
#pragma unroll
  for (int s=0;s<8;s++){
    f16x8 b = *(const f16x8*)(&HB[col][s*32 + quad*8]);
    f16x8 a = *(const f16x8*)(wb + (size_t)(wv*8+s)*512);
    acc = __builtin_amdgcn_mfma_f32_16x16x32_f16(a, b, acc, 0,0,0);
  }

  const int outb = wv*16 + quad*4;
  const int node = n0 + col;
  float4 gbv = *(const float4*)(gb + outb);
  float4 hv  = *(const float4*)(h + (size_t)node*HID + outb);
  float4 av  = *(const float4*)(&Agg[col][outb]);
  float gg[4] = {gbv.x,gbv.y,gbv.z,gbv.w};
  float hh[4] = {hv.x,hv.y,hv.z,hv.w};
  float aa[4] = {av.x,av.y,av.z,av.w};
  float vv[4], ss=0.f, ss2=0.f;
#pragma unroll
  for (int r=0;r<4;r++){
    float gate = fsig(acc[r] + gg[r]);
    float v = hh[r] + gate*aa[r] + (1.f-gate)*hh[r];
    vv[r] = v; ss += v; ss2 += v*v;
  }
  ss  += __shfl_xor(ss, 16, 64);  ss  += __shfl_xor(ss, 32, 64);
  ss2 += __shfl_xor(ss2, 16, 64); ss2 += __shfl_xor(ss2, 32, 64);
  if (quad == 0){ reds[wv][col] = ss; reds2[wv][col] = ss2; }
  __syncthreads();

  float S=0.f, S2=0.f;
#pragma unroll
  for (int w=0;w<8;w++){ S += reds[w][col]; S2 += reds2[w][col]; }
  float mean = S*(1.f/128.f);
  float var  = S2*(1.f/128.f) - mean*mean;
  float rsq  = rsqrtf(var + 1e-5f);
  float4 gv = *(const float4*)(lng + outb);
  float4 bv = *(const float4*)(lnb + outb);
  float gvl[4] = {gv.x,gv.y,gv.z,gv.w};
  float bvl[4] = {bv.x,bv.y,bv.z,bv.w};
  float4 outv; float* ov = (float*)&outv;
  float o0 = (vv[0]-mean)*rsq*gvl[0] + bvl[0];
  float o1 = (vv[1]-mean)*rsq*gvl[1] + bvl[1];
  float o2 = (vv[2]-mean)*rsq*gvl[2] + bvl[2];
  float o3 = (vv[3]-mean)*rsq*gvl[3] + bvl[3];
  ov[0]=o0; ov[1]=o1; ov[2]=o2; ov[3]=o3;
  *(float4*)(hout + (size_t)node*HID + outb) = outv;
  union { f16x2 h2[2]; uint2 u; } pk;
  pk.h2[0] = __builtin_amdgcn_cvt_pkrtz(o0,o1);
  pk.h2[1] = __builtin_amdgcn_cvt_pkrtz(o2,o3);
  *(uint2*)(hfout + (size_t)node*HID + outb) = pk.u;
}

// ---------------- pooling: segmented sums (batch is sorted) ----------------
__global__ void k_pool(const float* __restrict__ h, const int* __restrict__ batch,
                       float* __restrict__ sums, float* __restrict__ counts){
  const int c = threadIdx.x;
  const int n0 = blockIdx.x * 8;
  int cur = batch[n0];
  float local = 0.f, cnt = 0.f;
  for (int i=0;i<8;i++){
    int n = n0 + i;
    int g = batch[n];
    if (g != cur){
      atomicAdd(&sums[cur*HID + c], local);
      if (c==0) atomicAdd(&counts[cur], cnt);
      local = 0.f; cnt = 0.f; cur = g;
    }
    local += h[(size_t)n*HID + c];
    cnt += 1.f;
  }
  atomicAdd(&sums[cur*HID + c], local);
  if (c==0) atomicAdd(&counts[cur], cnt);
}

// ---------------- x_global + projector ----------------
__global__ void k_final(const float* __restrict__ sums, const float* __restrict__ counts,
    const float* __restrict__ p1W, const float* __restrict__ p1b,
    const float* __restrict__ l1g, const float* __restrict__ l1b,
    const float* __restrict__ p2W, const float* __restrict__ p2b,
    const float* __restrict__ l2g, const float* __restrict__ l2b,
    float* __restrict__ out){
  const int g = blockIdx.x, c = threadIdx.x;
  __shared__ float xg[HID], p[HID], red[4];
  float cnt = counts[g];
  float s = sums[g*HID + c];
  float xgv = s * (1.f/fmaxf(cnt,1.f) + 1.f/(cnt + 1e-6f));
  out[NG*64 + g*HID + c] = xgv;
  xg[c] = xgv;
  __syncthreads();
  float v = p1b[c];
  for (int k=0;k<HID;k++) v += xg[k]*p1W[c*HID + k];
  float sv=v, sv2=v*v;
#pragma unroll
  for (int m=1;m<64;m<<=1){ sv+=__shfl_xor(sv,m,64); sv2+=__shfl_xor(sv2,m,64); }
  if ((c&63)==0){ red[(c>>6)*2]=sv; red[(c>>6)*2+1]=sv2; }
  __syncthreads();
  float S=red[0]+red[2], S2=red[1]+red[3];
  float mean=S*(1.f/128.f), var=S2*(1.f/128.f)-mean*mean;
  float y=(v-mean)*rsqrtf(var+1e-5f)*l1g[c]+l1b[c];
  p[c] = y*fsig(y);
  __syncthreads();
  if (c < 64){
    float z = p2b[c];
    for (int k=0;k<HID;k++) z += p[k]*p2W[c*HID + k];
    float t=z, t2=z*z;
#pragma unroll
    for (int m=1;m<64;m<<=1){ t+=__shfl_xor(t,m,64); t2+=__shfl_xor(t2,m,64); }
    float mn=t*(1.f/64.f), vr=t2*(1.f/64.f)-mn*mn;
    out[g*64 + c] = (z-mn)*rsqrtf(vr+1e-5f)*l2g[c]+l2b[c];
  }
}

extern "C" void kernel_launch(void* const* d_in, const int* in_sizes, int n_in,
                              void* d_out, int out_size, void* d_ws, size_t ws_size,
                              hipStream_t stream){
  const float* x     = (const float*)d_in[0];
  const float* ea    = (const float*)d_in[1];
  const int*   ei    = (const int*)  d_in[2];
  const int*   batch = (const int*)  d_in[3];
  const float* embW  = (const float*)d_in[4];
  const float* embB  = (const float*)d_in[5];
  const float* embG  = (const float*)d_in[6];
  const float* embBe = (const float*)d_in[7];
  const float* m1W   = (const float*)d_in[8];
  const float* m1b   = (const float*)d_in[9];
  const float* m2W   = (const float*)d_in[10];
  const float* m2b   = (const float*)d_in[11];
  const float* gW    = (const float*)d_in[12];
  const float* gb    = (const float*)d_in[13];
  const float* lng   = (const float*)d_in[14];
  const float* lnb   = (const float*)d_in[15];
  const float* p1W   = (const float*)d_in[16];
  const float* p1b   = (const float*)d_in[17];
  const float* l1g   = (const float*)d_in[18];
  const float* l1b   = (const float*)d_in[19];
  const float* p2W   = (const float*)d_in[20];
  const float* p2b   = (const float*)d_in[21];
  const float* l2g   = (const float*)d_in[22];
  const float* l2b   = (const float*)d_in[23];

  char* p = (char*)d_ws;
  auto alloc = [&](size_t bytes){ char* r = p; p += (bytes + 255) & ~(size_t)255; return r; };
  float*     h    = (float*)     alloc((size_t)NNP*HID*4);
  _Float16*  hf   = (_Float16*)  alloc((size_t)NNP*HID*2);
  _Float16*  UV   = (_Float16*)  alloc((size_t)NNP*512*2);
  _Float16*  msg  = (_Float16*)  alloc((size_t)NE*HID*2);
  _Float16*  wnf  = (_Float16*)  alloc((size_t)NL*65536*2);
  _Float16*  w2f  = (_Float16*)  alloc((size_t)NL*32768*2);
  _Float16*  gwf  = (_Float16*)  alloc((size_t)NL*32768*2);
  float*     w256 = (float*)     alloc((size_t)NL*256*4);
  float*     biasUV=(float*)     alloc((size_t)NL*512*4);
  int*       deg  = (int*)       alloc((size_t)2*NNP*4);     // deg + cursor contiguous
  int*       cursor = deg + NNP;
  int*       rs   = (int*)       alloc((size_t)(NNP+1)*4);
  int*       esrc = (int*)       alloc((size_t)NE*4);
  int*       edst = (int*)       alloc((size_t)NE*4);
  float*     eas  = (float*)     alloc((size_t)NE*4);
  float*     sums = (float*)     alloc((size_t)(NG*HID+NG)*4); // sums + counts contiguous
  float*     counts = sums + NG*HID;

  hipMemsetAsync(deg, 0, (size_t)2*NNP*4, stream);
  hipMemsetAsync(sums, 0, (size_t)(NG*HID+NG)*4, stream);

  const int PT = NL*65536 + 2*NL*32768 + NL*256 + NL*512;
  k_prep<<<(PT+255)/256, 256, 0, stream>>>(m1W, m2W, gW, m1b, wnf, w2f, gwf, w256, biasUV);
  k_embed<<<NNP/2, 256, 0, stream>>>(x, embW, embB, embG, embBe, h, hf);
  k_hist<<<NE/256, 256, 0, stream>>>(ei, deg);
  k_scan<<<1, 256, 0, stream>>>(deg, rs);
  k_rank<<<NE/256, 256, 0, stream>>>(ei, ea, rs, cursor, esrc, edst, eas);

  for (int l=0; l<NL; l++){
    k_nodeUV<<<NNP/16, 256, 0, stream>>>(hf, wnf + (size_t)l*65536, biasUV + l*512, UV);
    k_edge<<<NE/128, 256, 0, stream>>>(UV, esrc, edst, eas,
                                       w256 + l*256, w2f + (size_t)l*32768,
                                       m2b + l*128, msg);
    k_update<<<NNP/16, 512, 0, stream>>>(hf, h, msg, rs,
                                         gwf + (size_t)l*32768, gb + l*128,
                                         lng + l*128, lnb + l*128, h, hf);
  }
  k_pool<<<NN/8, 128, 0, stream>>>(h, batch, sums, counts);
  k_final<<<NG, 128, 0, stream>>>(sums, counts, p1W, p1b, l1g, l1b,
                                  p2W, p2b, l2g, l2b, (float*)d_out);
}

// Round 7
// 331.496 us; speedup vs baseline: 6.1633x; 1.2561x over previous
//
#include <hip/hip_runtime.h>

#define NN 10000
#define NNP 10048
#define NE 160000
#define NG 64
#define HID 128
#define NL 3

typedef float floatx4 __attribute__((ext_vector_type(4)));
typedef _Float16 f16x8 __attribute__((ext_vector_type(8)));
typedef __fp16 f16x2 __attribute__((ext_vector_type(2)));   // return type of cvt_pkrtz

__device__ __forceinline__ float fsig(float x){
  return __builtin_amdgcn_rcpf(1.f + __expf(-x));
}

// ---------------- prep: repack weights into fp16 MFMA A-fragment layouts ----------------
// wnf: [l][512 out][128 k]  rows 0..255 = W1[:,0:128] (dst part), 256..511 = W1[:,128:256] (src)
//   frag idx = (((mb*4+s)*4+quad)*16+col)*8+t ; out=mb*16+col, k=s*32+quad*8+t
// w2f/gwf: [l][128 out][256 k], frag idx = (((mb*8+s)*4+quad)*16+col)*8+t
__global__ void k_prep(const float* __restrict__ m1, const float* __restrict__ m2,
                       const float* __restrict__ mg, const float* __restrict__ m1b,
                       _Float16* __restrict__ wnf, _Float16* __restrict__ w2f,
                       _Float16* __restrict__ gwf,
                       float* __restrict__ w256, float* __restrict__ biasUV){
  int i = blockIdx.x*256 + threadIdx.x;
  const int A = NL*65536;
  const int B = A + NL*32768;
  const int C = B + NL*32768;
  const int D = C + NL*256;
  const int E = D + NL*512;
  if (i < A){
    int l = i>>16, j = i&65535;
    int t=j&7, col=(j>>3)&15, quad=(j>>7)&3, s=(j>>9)&3, mb=(j>>11)&31;
    int o = mb*16+col, k = s*32+quad*8+t;
    float v = (o < 256) ? m1[l*65792 + o*257 + k] : m1[l*65792 + (o-256)*257 + 128 + k];
    wnf[i] = (_Float16)v;
  } else if (i < B){
    int j = i-A; int l = j>>15; j &= 32767;
    int t=j&7, col=(j>>3)&15, quad=(j>>7)&3, s=(j>>9)&7, mb=(j>>12)&7;
    w2f[(l<<15)+j] = (_Float16)m2[l*32768 + (mb*16+col)*256 + s*32+quad*8+t];
  } else if (i < C){
    int j = i-B; int l = j>>15; j &= 32767;
    int t=j&7, col=(j>>3)&15, quad=(j>>7)&3, s=(j>>9)&7, mb=(j>>12)&7;
    gwf[(l<<15)+j] = (_Float16)mg[l*32768 + (mb*16+col)*256 + s*32+quad*8+t];
  } else if (i < D){
    int j = i-C; int l = j>>8, o = j&255;
    w256[j] = m1[l*65792 + o*257 + 256];
  } else if (i < E){
    int j = i-D; int o = j&511;
    biasUV[j] = (o < 256) ? m1b[(j>>9)*256 + o] : 0.f;
  }
}

// ---------------- CSR build ----------------
__global__ void k_hist(const int* __restrict__ ei, int* __restrict__ deg){
  int e = blockIdx.x*256 + threadIdx.x;
  atomicAdd(&deg[ei[NE + e]], 1);
}

__global__ void k_scan(const int* __restrict__ deg, int* __restrict__ rs){
  __shared__ int ps[257];
  const int t = threadIdx.x;
  const int base = t*40;
  int s = 0;
  for (int i=0;i<40;i++){ int idx=base+i; if (idx<NNP) s += deg[idx]; }
  ps[t+1] = s;
  __syncthreads();
  if (t==0){ ps[0]=0; for (int i=1;i<=256;i++) ps[i]+=ps[i-1]; }
  __syncthreads();
  int run = ps[t];
  for (int i=0;i<40;i++){ int idx=base+i; if (idx<NNP){ rs[idx]=run; run+=deg[idx]; } }
  if (t==255) rs[NNP] = ps[256];
}

__global__ void k_rank(const int* __restrict__ ei, const float* __restrict__ ea,
                       const int* __restrict__ rs, int* __restrict__ cursor,
                       int* __restrict__ esrc, int* __restrict__ edst,
                       float* __restrict__ eas){
  int e = blockIdx.x*256 + threadIdx.x;
  int d = ei[NE + e];
  int pos = rs[d] + atomicAdd(&cursor[d], 1);
  esrc[pos] = ei[e];
  edst[pos] = d;
  eas[pos]  = ea[e];
}

// ---------------- node embedding (2 nodes per 256-thr block) ----------------
__global__ void k_embed(const float* __restrict__ x, const float* __restrict__ W,
                        const float* __restrict__ b, const float* __restrict__ g,
                        const float* __restrict__ bb, float* __restrict__ h,
                        _Float16* __restrict__ hf){
  const int tid = threadIdx.x;
  const int nn = tid>>7, c = tid&127;
  const int n = blockIdx.x*2 + nn;
  __shared__ float red[2][2][2];
  float x0=0.f, x1=0.f, x2=0.f;
  if (n < NN){ x0 = x[n*3]; x1 = x[n*3+1]; x2 = x[n*3+2]; }
  float v = W[c*3]*x0 + W[c*3+1]*x1 + W[c*3+2]*x2 + b[c];
  float s = v, s2 = v*v;
#pragma unroll
  for (int m=1;m<64;m<<=1){ s += __shfl_xor(s,m,64); s2 += __shfl_xor(s2,m,64); }
  if ((c & 63) == 0){ red[nn][c>>6][0] = s; red[nn][c>>6][1] = s2; }
  __syncthreads();
  float S  = red[nn][0][0]+red[nn][1][0];
  float S2 = red[nn][0][1]+red[nn][1][1];
  float mean = S*(1.f/128.f);
  float var = S2*(1.f/128.f) - mean*mean;
  float y = (v-mean)*rsqrtf(var+1e-5f)*g[c] + bb[c];
  float o = y * fsig(y);
  h[(size_t)n*HID + c] = o;
  hf[(size_t)n*HID + c] = (_Float16)o;
}

// ---------------- node GEMM: UV[node][512] = [W1a.h + b1 ; W1b.h] (fp16) ----------------
__global__ __launch_bounds__(256) void k_nodeUV(
    const _Float16* __restrict__ hf,
    const _Float16* __restrict__ wnf, const float* __restrict__ biasUV,
    _Float16* __restrict__ UV)
{
  const int tid = threadIdx.x;
  const int wv = tid>>6, lane = tid&63;
  const int col = lane&15, quad = lane>>4;
  const int node = blockIdx.x*16 + col;

  f16x8 bfrag[4];
#pragma unroll
  for (int s=0;s<4;s++)
    bfrag[s] = *(const f16x8*)(hf + (size_t)node*HID + s*32 + quad*8);

  floatx4 acc[8];
#pragma unroll
  for (int i=0;i<8;i++) acc[i] = (floatx4)(0.f);

  const _Float16* wb = wnf + quad*128 + col*8;
#pragma unroll
  for (int s=0;s<4;s++)
#pragma unroll
    for (int mt=0;mt<8;mt++){
      f16x8 a = *(const f16x8*)(wb + (size_t)((wv*8+mt)*4+s)*512);
      acc[mt] = __builtin_amdgcn_mfma_f32_16x16x32_f16(a, bfrag[s], acc[mt], 0,0,0);
    }

#pragma unroll
  for (int mt=0;mt<8;mt++){
    int o0 = wv*128 + mt*16 + quad*4;
    float4 bv = *(const float4*)(biasUV + o0);
    union { f16x2 h2[2]; uint2 u; } pk;
    pk.h2[0] = __builtin_amdgcn_cvt_pkrtz(acc[mt][0]+bv.x, acc[mt][1]+bv.y);
    pk.h2[1] = __builtin_amdgcn_cvt_pkrtz(acc[mt][2]+bv.z, acc[mt][3]+bv.w);
    *(uint2*)(UV + (size_t)node*512 + o0) = pk.u;
  }
}

// ---------------- edge aggregation: aggP[n] = sum_e silu(U[n]+V[src]+ea*w256) ----------------
// One wave per node; lane covers 4 of 256 dims; fp32 accumulate; fp16 output.
__global__ __launch_bounds__(256) void k_agg(
    const _Float16* __restrict__ UV,
    const int* __restrict__ esrc, const float* __restrict__ eas,
    const int* __restrict__ rs, const float* __restrict__ w256,
    _Float16* __restrict__ aggP)
{
  const int tid = threadIdx.x;
  const int n = blockIdx.x*4 + (tid>>6);
  const int el = (tid & 63) * 4;

  union { uint2 u; _Float16 hx[4]; } uu;
  uu.u = *(const uint2*)(UV + (size_t)n*512 + el);
  float U0=(float)uu.hx[0], U1=(float)uu.hx[1], U2=(float)uu.hx[2], U3=(float)uu.hx[3];
  float4 wc = *(const float4*)(w256 + el);

  float a0=0.f,a1=0.f,a2=0.f,a3=0.f;
  int rb = rs[n], re = rs[n+1];
  if (rb < re){
    int src = esrc[rb];
    float ean = eas[rb];
    uint2 vb = *(const uint2*)(UV + (size_t)src*512 + 256 + el);
    for (int r=rb; r<re; r++){
      union { uint2 u; _Float16 hx[4]; } vv; vv.u = vb;
      float ea = ean;
      if (r+1 < re){
        int s2 = esrc[r+1];
        ean = eas[r+1];
        vb = *(const uint2*)(UV + (size_t)s2*512 + 256 + el);
      }
      float f0 = U0 + (float)vv.hx[0] + ea*wc.x;
      float f1 = U1 + (float)vv.hx[1] + ea*wc.y;
      float f2 = U2 + (float)vv.hx[2] + ea*wc.z;
      float f3 = U3 + (float)vv.hx[3] + ea*wc.w;
      a0 += f0*fsig(f0); a1 += f1*fsig(f1);
      a2 += f2*fsig(f2); a3 += f3*fsig(f3);
    }
  }
  union { f16x2 h2[2]; uint2 u; } pk;
  pk.h2[0] = __builtin_amdgcn_cvt_pkrtz(a0,a1);
  pk.h2[1] = __builtin_amdgcn_cvt_pkrtz(a2,a3);
  *(uint2*)(aggP + (size_t)n*256 + el) = pk.u;
}

// ---------------- GEMM2 (aggregated) + gate MFMA + residual + LN (16 nodes/block) ----------------
__global__ __launch_bounds__(256) void k_upd2(
    const _Float16* __restrict__ hf, const float* __restrict__ h,
    const _Float16* __restrict__ aggP, const int* __restrict__ rs,
    const _Float16* __restrict__ w2f, const float* __restrict__ b2,
    const _Float16* __restrict__ gwf, const float* __restrict__ gb,
    const float* __restrict__ lng, const float* __restrict__ lnb,
    float* __restrict__ hout, _Float16* __restrict__ hfout)
{
  __shared__ _Float16 HB[16][264];   // [node][k] fp16: k<128 h, k>=128 aggr
  __shared__ float Agg[16][132];
  __shared__ float reds[4][16], reds2[4][16];
  const int tid = threadIdx.x;
  const int wv = tid>>6, lane = tid&63;
  const int col = lane&15, quad = lane>>4;
  const int n0 = blockIdx.x*16;

  { // stage hf rows (fp16), 16 threads per node, 16B each
    int n = tid>>4, c = tid&15;
    *(uint4*)(&HB[n][c*8]) = *(const uint4*)(hf + (size_t)(n0+n)*HID + c*8);
  }

  // ---- GEMM2: aggr = W2 . aggP^T  (+ deg*b2) ; wave wv -> outs [wv*32,+32) ----
  floatx4 acc[2]; acc[0]=(floatx4)(0.f); acc[1]=(floatx4)(0.f);
  const _Float16* wb2 = w2f + quad*128 + col*8;
  const _Float16* bp  = aggP + (size_t)(n0+col)*256 + quad*8;
#pragma unroll
  for (int s=0;s<8;s++){
    f16x8 b = *(const f16x8*)(bp + s*32);
#pragma unroll
    for (int mt=0;mt<2;mt++){
      f16x8 a = *(const f16x8*)(wb2 + (size_t)((wv*2+mt)*8+s)*512);
      acc[mt] = __builtin_amdgcn_mfma_f32_16x16x32_f16(a, b, acc[mt], 0,0,0);
    }
  }
  float deg = (float)(rs[n0+col+1] - rs[n0+col]);
#pragma unroll
  for (int mt=0;mt<2;mt++){
    int outb = (wv*2+mt)*16 + quad*4;
    float4 b2v = *(const float4*)(b2 + outb);
    float v0 = acc[mt][0] + deg*b2v.x;
    float v1 = acc[mt][1] + deg*b2v.y;
    float v2 = acc[mt][2] + deg*b2v.z;
    float v3 = acc[mt][3] + deg*b2v.w;
    *(float4*)(&Agg[col][outb]) = make_float4(v0,v1,v2,v3);
    union { f16x2 h2[2]; uint2 u; } pk;
    pk.h2[0] = __builtin_amdgcn_cvt_pkrtz(v0,v1);
    pk.h2[1] = __builtin_amdgcn_cvt_pkrtz(v2,v3);
    *(uint2*)(&HB[col][128+outb]) = pk.u;
  }
  __syncthreads();

  // ---- gate GEMM: wave wv -> outs [wv*32,+32) over [h;aggr] ----
  floatx4 acc2[2]; acc2[0]=(floatx4)(0.f); acc2[1]=(floatx4)(0.f);
  const _Float16* wbg = gwf + quad*128 + col*8;
#pragma unroll
  for (int s=0;s<8;s++){
    f16x8 b = *(const f16x8*)(&HB[col][s*32 + quad*8]);
#pragma unroll
    for (int mt=0;mt<2;mt++){
      f16x8 a = *(const f16x8*)(wbg + (size_t)((wv*2+mt)*8+s)*512);
      acc2[mt] = __builtin_amdgcn_mfma_f32_16x16x32_f16(a, b, acc2[mt], 0,0,0);
    }
  }

  // epilogue: gate, residual; LN partials
  const int node = n0 + col;
  float vv[2][4], ss=0.f, ss2=0.f;
#pragma unroll
  for (int mt=0;mt<2;mt++){
    int outb = (wv*2+mt)*16 + quad*4;
    float4 gbv = *(const float4*)(gb + outb);
    float4 hv  = *(const float4*)(h + (size_t)node*HID + outb);
    float4 av  = *(const float4*)(&Agg[col][outb]);
    float gg[4] = {gbv.x,gbv.y,gbv.z,gbv.w};
    float hh[4] = {hv.x,hv.y,hv.z,hv.w};
    float aa[4] = {av.x,av.y,av.z,av.w};
#pragma unroll
    for (int r=0;r<4;r++){
      float gate = fsig(acc2[mt][r] + gg[r]);
      float v = hh[r] + gate*aa[r] + (1.f-gate)*hh[r];
      vv[mt][r] = v; ss += v; ss2 += v*v;
    }
  }
  ss  += __shfl_xor(ss, 16, 64);  ss  += __shfl_xor(ss, 32, 64);
  ss2 += __shfl_xor(ss2, 16, 64); ss2 += __shfl_xor(ss2, 32, 64);
  if (quad == 0){ reds[wv][col] = ss; reds2[wv][col] = ss2; }
  __syncthreads();

  float S  = reds[0][col]+reds[1][col]+reds[2][col]+reds[3][col];
  float S2 = reds2[0][col]+reds2[1][col]+reds2[2][col]+reds2[3][col];
  float mean = S*(1.f/128.f);
  float var  = S2*(1.f/128.f) - mean*mean;
  float rsq  = rsqrtf(var + 1e-5f);
#pragma unroll
  for (int mt=0;mt<2;mt++){
    int outb = (wv*2+mt)*16 + quad*4;
    float4 gv = *(const float4*)(lng + outb);
    float4 bv = *(const float4*)(lnb + outb);
    float gvl[4] = {gv.x,gv.y,gv.z,gv.w};
    float bvl[4] = {bv.x,bv.y,bv.z,bv.w};
    float4 outv; float* ov = (float*)&outv;
    float o0 = (vv[mt][0]-mean)*rsq*gvl[0] + bvl[0];
    float o1 = (vv[mt][1]-mean)*rsq*gvl[1] + bvl[1];
    float o2 = (vv[mt][2]-mean)*rsq*gvl[2] + bvl[2];
    float o3 = (vv[mt][3]-mean)*rsq*gvl[3] + bvl[3];
    ov[0]=o0; ov[1]=o1; ov[2]=o2; ov[3]=o3;
    *(float4*)(hout + (size_t)node*HID + outb) = outv;
    union { f16x2 h2[2]; uint2 u; } pk;
    pk.h2[0] = __builtin_amdgcn_cvt_pkrtz(o0,o1);
    pk.h2[1] = __builtin_amdgcn_cvt_pkrtz(o2,o3);
    *(uint2*)(hfout + (size_t)node*HID + outb) = pk.u;
  }
}

// ---------------- pooling: segmented sums (batch is sorted) ----------------
__global__ void k_pool(const float* __restrict__ h, const int* __restrict__ batch,
                       float* __restrict__ sums, float* __restrict__ counts){
  const int c = threadIdx.x;
  const int n0 = blockIdx.x * 8;
  int cur = batch[n0];
  float local = 0.f, cnt = 0.f;
  for (int i=0;i<8;i++){
    int n = n0 + i;
    int g = batch[n];
    if (g != cur){
      atomicAdd(&sums[cur*HID + c], local);
      if (c==0) atomicAdd(&counts[cur], cnt);
      local = 0.f; cnt = 0.f; cur = g;
    }
    local += h[(size_t)n*HID + c];
    cnt += 1.f;
  }
  atomicAdd(&sums[cur*HID + c], local);
  if (c==0) atomicAdd(&counts[cur], cnt);
}

// ---------------- x_global + projector ----------------
__global__ void k_final(const float* __restrict__ sums, const float* __restrict__ counts,
    const float* __restrict__ p1W, const float* __restrict__ p1b,
    const float* __restrict__ l1g, const float* __restrict__ l1b,
    const float* __restrict__ p2W, const float* __restrict__ p2b,
    const float* __restrict__ l2g, const float* __restrict__ l2b,
    float* __restrict__ out){
  const int g = blockIdx.x, c = threadIdx.x;
  __shared__ float xg[HID], p[HID], red[4];
  float cnt = counts[g];
  float s = sums[g*HID + c];
  float xgv = s * (1.f/fmaxf(cnt,1.f) + 1.f/(cnt + 1e-6f));
  out[NG*64 + g*HID + c] = xgv;
  xg[c] = xgv;
  __syncthreads();
  float v = p1b[c];
  for (int k=0;k<HID;k++) v += xg[k]*p1W[c*HID + k];
  float sv=v, sv2=v*v;
#pragma unroll
  for (int m=1;m<64;m<<=1){ sv+=__shfl_xor(sv,m,64); sv2+=__shfl_xor(sv2,m,64); }
  if ((c&63)==0){ red[(c>>6)*2]=sv; red[(c>>6)*2+1]=sv2; }
  __syncthreads();
  float S=red[0]+red[2], S2=red[1]+red[3];
  float mean=S*(1.f/128.f), var=S2*(1.f/128.f)-mean*mean;
  float y=(v-mean)*rsqrtf(var+1e-5f)*l1g[c]+l1b[c];
  p[c] = y*fsig(y);
  __syncthreads();
  if (c < 64){
    float z = p2b[c];
    for (int k=0;k<HID;k++) z += p[k]*p2W[c*HID + k];
    float t=z, t2=z*z;
#pragma unroll
    for (int m=1;m<64;m<<=1){ t+=__shfl_xor(t,m,64); t2+=__shfl_xor(t2,m,64); }
    float mn=t*(1.f/64.f), vr=t2*(1.f/64.f)-mn*mn;
    out[g*64 + c] = (z-mn)*rsqrtf(vr+1e-5f)*l2g[c]+l2b[c];
  }
}

extern "C" void kernel_launch(void* const* d_in, const int* in_sizes, int n_in,
                              void* d_out, int out_size, void* d_ws, size_t ws_size,
                              hipStream_t stream){
  const float* x     = (const float*)d_in[0];
  const float* ea    = (const float*)d_in[1];
  const int*   ei    = (const int*)  d_in[2];
  const int*   batch = (const int*)  d_in[3];
  const float* embW  = (const float*)d_in[4];
  const float* embB  = (const float*)d_in[5];
  const float* embG  = (const float*)d_in[6];
  const float* embBe = (const float*)d_in[7];
  const float* m1W   = (const float*)d_in[8];
  const float* m1b   = (const float*)d_in[9];
  const float* m2W   = (const float*)d_in[10];
  const float* m2b   = (const float*)d_in[11];
  const float* gW    = (const float*)d_in[12];
  const float* gb    = (const float*)d_in[13];
  const float* lng   = (const float*)d_in[14];
  const float* lnb   = (const float*)d_in[15];
  const float* p1W   = (const float*)d_in[16];
  const float* p1b   = (const float*)d_in[17];
  const float* l1g   = (const float*)d_in[18];
  const float* l1b   = (const float*)d_in[19];
  const float* p2W   = (const float*)d_in[20];
  const float* p2b   = (const float*)d_in[21];
  const float* l2g   = (const float*)d_in[22];
  const float* l2b   = (const float*)d_in[23];

  char* p = (char*)d_ws;
  auto alloc = [&](size_t bytes){ char* r = p; p += (bytes + 255) & ~(size_t)255; return r; };
  float*     h    = (float*)     alloc((size_t)NNP*HID*4);
  _Float16*  hf   = (_Float16*)  alloc((size_t)NNP*HID*2);
  _Float16*  UV   = (_Float16*)  alloc((size_t)NNP*512*2);
  _Float16*  aggP = (_Float16*)  alloc((size_t)NNP*256*2);
  _Float16*  wnf  = (_Float16*)  alloc((size_t)NL*65536*2);
  _Float16*  w2f  = (_Float16*)  alloc((size_t)NL*32768*2);
  _Float16*  gwf  = (_Float16*)  alloc((size_t)NL*32768*2);
  float*     w256 = (float*)     alloc((size_t)NL*256*4);
  float*     biasUV=(float*)     alloc((size_t)NL*512*4);
  int*       deg  = (int*)       alloc((size_t)2*NNP*4);     // deg + cursor contiguous
  int*       cursor = deg + NNP;
  int*       rs   = (int*)       alloc((size_t)(NNP+1)*4);
  int*       esrc = (int*)       alloc((size_t)NE*4);
  int*       edst = (int*)       alloc((size_t)NE*4);
  float*     eas  = (float*)     alloc((size_t)NE*4);
  float*     sums = (float*)     alloc((size_t)(NG*HID+NG)*4); // sums + counts contiguous
  float*     counts = sums + NG*HID;

  hipMemsetAsync(deg, 0, (size_t)2*NNP*4, stream);
  hipMemsetAsync(sums, 0, (size_t)(NG*HID+NG)*4, stream);

  const int PT = NL*65536 + 2*NL*32768 + NL*256 + NL*512;
  k_prep<<<(PT+255)/256, 256, 0, stream>>>(m1W, m2W, gW, m1b, wnf, w2f, gwf, w256, biasUV);
  k_embed<<<NNP/2, 256, 0, stream>>>(x, embW, embB, embG, embBe, h, hf);
  k_hist<<<NE/256, 256, 0, stream>>>(ei, deg);
  k_scan<<<1, 256, 0, stream>>>(deg, rs);
  k_rank<<<NE/256, 256, 0, stream>>>(ei, ea, rs, cursor, esrc, edst, eas);

  for (int l=0; l<NL; l++){
    k_nodeUV<<<NNP/16, 256, 0, stream>>>(hf, wnf + (size_t)l*65536, biasUV + l*512, UV);
    k_agg<<<NNP/4, 256, 0, stream>>>(UV, esrc, eas, rs, w256 + l*256, aggP);
    k_upd2<<<NNP/16, 256, 0, stream>>>(hf, h, aggP, rs,
                                       w2f + (size_t)l*32768, m2b + l*128,
                                       gwf + (size_t)l*32768, gb + l*128,
                                       lng + l*128, lnb + l*128, h, hf);
  }
  k_pool<<<NN/8, 128, 0, stream>>>(h, batch, sums, counts);
  k_final<<<NG, 128, 0, stream>>>(sums, counts, p1W, p1b, l1g, l1b,
                                  p2W, p2b, l2g, l2b, (float*)d_out);
}

// Round 8
// 299.982 us; speedup vs baseline: 6.8107x; 1.1051x over previous
//
#include <hip/hip_runtime.h>

#define NN 10000
#define NNP 10048
#define NE 160000
#define NG 64
#define HID 128
#define NL 3

typedef float floatx4 __attribute__((ext_vector_type(4)));
typedef _Float16 f16x8 __attribute__((ext_vector_type(8)));
typedef __fp16 f16x2 __attribute__((ext_vector_type(2)));   // return type of cvt_pkrtz

__device__ __forceinline__ float fsig(float x){
  return __builtin_amdgcn_rcpf(1.f + __expf(-x));
}

// prep sizes
#define SZ_A (NL*65536)            // wnf
#define SZ_B (SZ_A + NL*32768)     // w2f
#define SZ_C (SZ_B + NL*32768)     // gwf
#define SZ_D (SZ_C + NL*256)       // w256
#define SZ_E (SZ_D + NL*512)       // biasUV
#define PT   SZ_E
#define SETUP_B ((PT + NE + 255)/256)

// ---------------- setup: weight repack + degree histogram + node embedding ----------------
// wnf: [l][512 out][128 k] rows 0..255 = W1[:,0:128] (dst), 256..511 = W1[:,128:256] (src)
//   frag idx = (((mb*4+s)*4+quad)*16+col)*8+t ; out=mb*16+col, k=s*32+quad*8+t
// w2f/gwf: [l][128 out][256 k], frag idx = (((mb*8+s)*4+quad)*16+col)*8+t
__global__ __launch_bounds__(256) void k_setup(
    const float* __restrict__ m1, const float* __restrict__ m2,
    const float* __restrict__ mg, const float* __restrict__ m1b,
    _Float16* __restrict__ wnf, _Float16* __restrict__ w2f,
    _Float16* __restrict__ gwf, float* __restrict__ w256,
    float* __restrict__ biasUV,
    const int* __restrict__ ei, int* __restrict__ deg,
    const float* __restrict__ x, const float* __restrict__ eW,
    const float* __restrict__ eB, const float* __restrict__ eG,
    const float* __restrict__ eBB,
    float* __restrict__ h, _Float16* __restrict__ hf)
{
  if (blockIdx.x < SETUP_B){
    int i = blockIdx.x*256 + threadIdx.x;
    if (i < SZ_A){
      int l = i>>16, j = i&65535;
      int t=j&7, col=(j>>3)&15, quad=(j>>7)&3, s=(j>>9)&3, mb=(j>>11)&31;
      int o = mb*16+col, k = s*32+quad*8+t;
      float v = (o < 256) ? m1[l*65792 + o*257 + k] : m1[l*65792 + (o-256)*257 + 128 + k];
      wnf[i] = (_Float16)v;
    } else if (i < SZ_B){
      int j = i-SZ_A; int l = j>>15; j &= 32767;
      int t=j&7, col=(j>>3)&15, quad=(j>>7)&3, s=(j>>9)&7, mb=(j>>12)&7;
      w2f[(l<<15)+j] = (_Float16)m2[l*32768 + (mb*16+col)*256 + s*32+quad*8+t];
    } else if (i < SZ_C){
      int j = i-SZ_B; int l = j>>15; j &= 32767;
      int t=j&7, col=(j>>3)&15, quad=(j>>7)&3, s=(j>>9)&7, mb=(j>>12)&7;
      gwf[(l<<15)+j] = (_Float16)mg[l*32768 + (mb*16+col)*256 + s*32+quad*8+t];
    } else if (i < SZ_D){
      int j = i-SZ_C; int l = j>>8, o = j&255;
      w256[j] = m1[l*65792 + o*257 + 256];
    } else if (i < SZ_E){
      int j = i-SZ_D; int o = j&511;
      biasUV[j] = (o < 256) ? m1b[(j>>9)*256 + o] : 0.f;
    } else if (i < PT + NE){
      atomicAdd(&deg[ei[NE + (i-PT)]], 1);
    }
    return;
  }
  // ---- embedding: 16 nodes per block, 16 threads per node ----
  int nb = blockIdx.x - SETUP_B;
  int node = nb*16 + (threadIdx.x>>4);
  int q = threadIdx.x & 15;
  float x0=0.f, x1=0.f, x2=0.f;
  if (node < NN){ x0 = x[node*3]; x1 = x[node*3+1]; x2 = x[node*3+2]; }
  float v[8], s=0.f, s2=0.f;
#pragma unroll
  for (int j=0;j<8;j++){
    int c = q*8+j;
    v[j] = eW[c*3]*x0 + eW[c*3+1]*x1 + eW[c*3+2]*x2 + eB[c];
    s += v[j]; s2 += v[j]*v[j];
  }
#pragma unroll
  for (int m=1;m<16;m<<=1){ s += __shfl_xor(s,m,64); s2 += __shfl_xor(s2,m,64); }
  float mean = s*(1.f/128.f);
  float var  = s2*(1.f/128.f) - mean*mean;
  float rsq  = rsqrtf(var + 1e-5f);
  float ho[8];
  union { f16x2 h2[4]; uint4 u; } pk;
#pragma unroll
  for (int j=0;j<8;j++){
    int c = q*8+j;
    float y = (v[j]-mean)*rsq*eG[c] + eBB[c];
    ho[j] = y * fsig(y);
  }
  pk.h2[0] = __builtin_amdgcn_cvt_pkrtz(ho[0],ho[1]);
  pk.h2[1] = __builtin_amdgcn_cvt_pkrtz(ho[2],ho[3]);
  pk.h2[2] = __builtin_amdgcn_cvt_pkrtz(ho[4],ho[5]);
  pk.h2[3] = __builtin_amdgcn_cvt_pkrtz(ho[6],ho[7]);
  *(float4*)(h + (size_t)node*HID + q*8)     = make_float4(ho[0],ho[1],ho[2],ho[3]);
  *(float4*)(h + (size_t)node*HID + q*8 + 4) = make_float4(ho[4],ho[5],ho[6],ho[7]);
  *(uint4*)(hf + (size_t)node*HID + q*8) = pk.u;
}

// ---------------- CSR scan + rank ----------------
__global__ void k_scan(const int* __restrict__ deg, int* __restrict__ rs){
  __shared__ int ps[257];
  const int t = threadIdx.x;
  const int base = t*40;
  int s = 0;
  for (int i=0;i<40;i++){ int idx=base+i; if (idx<NNP) s += deg[idx]; }
  ps[t+1] = s;
  __syncthreads();
  if (t==0){ ps[0]=0; for (int i=1;i<=256;i++) ps[i]+=ps[i-1]; }
  __syncthreads();
  int run = ps[t];
  for (int i=0;i<40;i++){ int idx=base+i; if (idx<NNP){ rs[idx]=run; run+=deg[idx]; } }
  if (t==255) rs[NNP] = ps[256];
}

__global__ void k_rank(const int* __restrict__ ei, const float* __restrict__ ea,
                       const int* __restrict__ rs, int* __restrict__ cursor,
                       int* __restrict__ esrc, float* __restrict__ eas){
  int e = blockIdx.x*256 + threadIdx.x;
  int d = ei[NE + e];
  int pos = rs[d] + atomicAdd(&cursor[d], 1);
  esrc[pos] = ei[e];
  eas[pos]  = ea[e];
}

// ---------------- node GEMM (layer 0 only): UV[node][512] = [W1a.h+b1 ; W1b.h] ----------------
__global__ __launch_bounds__(256) void k_nodeUV(
    const _Float16* __restrict__ hf,
    const _Float16* __restrict__ wnf, const float* __restrict__ biasUV,
    _Float16* __restrict__ UV)
{
  const int tid = threadIdx.x;
  const int wv = tid>>6, lane = tid&63;
  const int col = lane&15, quad = lane>>4;
  const int node = blockIdx.x*16 + col;

  f16x8 bfrag[4];
#pragma unroll
  for (int s=0;s<4;s++)
    bfrag[s] = *(const f16x8*)(hf + (size_t)node*HID + s*32 + quad*8);

  floatx4 acc[8];
#pragma unroll
  for (int i=0;i<8;i++) acc[i] = (floatx4)(0.f);

  const _Float16* wb = wnf + quad*128 + col*8;
#pragma unroll
  for (int s=0;s<4;s++)
#pragma unroll
    for (int mt=0;mt<8;mt++){
      f16x8 a = *(const f16x8*)(wb + (size_t)((wv*8+mt)*4+s)*512);
      acc[mt] = __builtin_amdgcn_mfma_f32_16x16x32_f16(a, bfrag[s], acc[mt], 0,0,0);
    }

#pragma unroll
  for (int mt=0;mt<8;mt++){
    int o0 = wv*128 + mt*16 + quad*4;
    float4 bv = *(const float4*)(biasUV + o0);
    union { f16x2 h2[2]; uint2 u; } pk;
    pk.h2[0] = __builtin_amdgcn_cvt_pkrtz(acc[mt][0]+bv.x, acc[mt][1]+bv.y);
    pk.h2[1] = __builtin_amdgcn_cvt_pkrtz(acc[mt][2]+bv.z, acc[mt][3]+bv.w);
    *(uint2*)(UV + (size_t)node*512 + o0) = pk.u;
  }
}

// ---------------- fused layer: agg + GEMM2 + gate + LN + next-layer UV ----------------
// 512 threads, 16 nodes/block. Only cross-block input: UVin (previous launch).
__global__ __launch_bounds__(512) void k_layer(
    const _Float16* __restrict__ UVin,
    const int* __restrict__ esrc, const float* __restrict__ eas,
    const int* __restrict__ rs,
    const float* __restrict__ w256,
    const _Float16* __restrict__ w2f, const float* __restrict__ b2,
    const _Float16* __restrict__ gwf, const float* __restrict__ gb,
    const float* __restrict__ lng, const float* __restrict__ lnb,
    const _Float16* __restrict__ hfin, const float* __restrict__ h,
    float* __restrict__ hout, _Float16* __restrict__ hfout,
    const float* __restrict__ biasUVn, const _Float16* __restrict__ wnfN,
    _Float16* __restrict__ UVout)
{
  __shared__ _Float16 HB[16][264];    // [node][k]: k<128 h (old, then new), k>=128 aggr
  __shared__ _Float16 AggH[16][264];  // silu-aggregate (fp16, GEMM2 B operand)
  __shared__ float Agg[16][132];      // GEMM2 output fp32 (gate residual operand)
  __shared__ float reds[8][16], reds2[8][16];
  const int tid = threadIdx.x;
  const int wv = tid>>6, lane = tid&63;
  const int col = lane&15, quad = lane>>4;
  const int n0 = blockIdx.x*16;

  { // stage old hf rows: 32 threads per node, 8 B each
    int n = tid>>5, c = tid&31;
    *(uint2*)(&HB[n][c*4]) = *(const uint2*)(hfin + (size_t)(n0+n)*HID + c*4);
  }

  // ---- phase A: aggregation. wave wv -> nodes {n0+wv*2, +1}; lane covers 4 dims ----
  const int el = lane*4;
  const float4 wc = *(const float4*)(w256 + el);
#pragma unroll
  for (int i=0;i<2;i++){
    int nl = wv*2 + i;
    int n = n0 + nl;
    union { uint2 u; _Float16 hx[4]; } uu;
    uu.u = *(const uint2*)(UVin + (size_t)n*512 + el);
    float U0=(float)uu.hx[0], U1=(float)uu.hx[1], U2=(float)uu.hx[2], U3=(float)uu.hx[3];
    float a0=0.f,a1=0.f,a2=0.f,a3=0.f;
    int rb = rs[n], re = rs[n+1];
    if (rb < re){
      int src = esrc[rb];
      float ean = eas[rb];
      uint2 vb = *(const uint2*)(UVin + (size_t)src*512 + 256 + el);
      for (int r=rb; r<re; r++){
        union { uint2 u; _Float16 hx[4]; } vv; vv.u = vb;
        float ea = ean;
        if (r+1 < re){
          int s2 = esrc[r+1];
          ean = eas[r+1];
          vb = *(const uint2*)(UVin + (size_t)s2*512 + 256 + el);
        }
        float f0 = U0 + (float)vv.hx[0] + ea*wc.x;
        float f1 = U1 + (float)vv.hx[1] + ea*wc.y;
        float f2 = U2 + (float)vv.hx[2] + ea*wc.z;
        float f3 = U3 + (float)vv.hx[3] + ea*wc.w;
        a0 += f0*fsig(f0); a1 += f1*fsig(f1);
        a2 += f2*fsig(f2); a3 += f3*fsig(f3);
      }
    }
    union { f16x2 h2[2]; uint2 u; } pk;
    pk.h2[0] = __builtin_amdgcn_cvt_pkrtz(a0,a1);
    pk.h2[1] = __builtin_amdgcn_cvt_pkrtz(a2,a3);
    *(uint2*)(&AggH[nl][el]) = pk.u;
  }
  __syncthreads();

  // ---- phase B: GEMM2 (aggregated): wave wv -> outs [wv*16,+16) ----
  floatx4 acc2 = (floatx4)(0.f);
  const _Float16* wb2 = w2f + quad*128 + col*8;
#pragma unroll
  for (int s=0;s<8;s++){
    f16x8 b = *(const f16x8*)(&AggH[col][s*32 + quad*8]);
    f16x8 a = *(const f16x8*)(wb2 + (size_t)(wv*8+s)*512);
    acc2 = __builtin_amdgcn_mfma_f32_16x16x32_f16(a, b, acc2, 0,0,0);
  }
  {
    float deg = (float)(rs[n0+col+1] - rs[n0+col]);
    int outb = wv*16 + quad*4;
    float4 b2v = *(const float4*)(b2 + outb);
    float v0 = acc2[0] + deg*b2v.x;
    float v1 = acc2[1] + deg*b2v.y;
    float v2 = acc2[2] + deg*b2v.z;
    float v3 = acc2[3] + deg*b2v.w;
    *(float4*)(&Agg[col][outb]) = make_float4(v0,v1,v2,v3);
    union { f16x2 h2[2]; uint2 u; } pk;
    pk.h2[0] = __builtin_amdgcn_cvt_pkrtz(v0,v1);
    pk.h2[1] = __builtin_amdgcn_cvt_pkrtz(v2,v3);
    *(uint2*)(&HB[col][128+outb]) = pk.u;
  }
  __syncthreads();

  // ---- phase C: gate GEMM over [h;aggr], residual, LN ----
  floatx4 accg = (floatx4)(0.f);
  const _Float16* wbg = gwf + quad*128 + col*8;
#pragma unroll
  for (int s=0;s<8;s++){
    f16x8 b = *(const f16x8*)(&HB[col][s*32 + quad*8]);
    f16x8 a = *(const f16x8*)(wbg + (size_t)(wv*8+s)*512);
    accg = __builtin_amdgcn_mfma_f32_16x16x32_f16(a, b, accg, 0,0,0);
  }
  const int outb = wv*16 + quad*4;
  const int node = n0 + col;
  float4 gbv = *(const float4*)(gb + outb);
  float4 hv  = *(const float4*)(h + (size_t)node*HID + outb);
  float4 av  = *(const float4*)(&Agg[col][outb]);
  float gg[4] = {gbv.x,gbv.y,gbv.z,gbv.w};
  float hh[4] = {hv.x,hv.y,hv.z,hv.w};
  float aa[4] = {av.x,av.y,av.z,av.w};
  float vvv[4], ss=0.f, ss2=0.f;
#pragma unroll
  for (int r=0;r<4;r++){
    float gate = fsig(accg[r] + gg[r]);
    float v = hh[r] + gate*aa[r] + (1.f-gate)*hh[r];
    vvv[r] = v; ss += v; ss2 += v*v;
  }
  ss  += __shfl_xor(ss, 16, 64);  ss  += __shfl_xor(ss, 32, 64);
  ss2 += __shfl_xor(ss2, 16, 64); ss2 += __shfl_xor(ss2, 32, 64);
  if (quad == 0){ reds[wv][col] = ss; reds2[wv][col] = ss2; }
  __syncthreads();

  float S=0.f, S2=0.f;
#pragma unroll
  for (int w=0;w<8;w++){ S += reds[w][col]; S2 += reds2[w][col]; }
  float mean = S*(1.f/128.f);
  float var  = S2*(1.f/128.f) - mean*mean;
  float rsq  = rsqrtf(var + 1e-5f);
  float4 gv = *(const float4*)(lng + outb);
  float4 bv = *(const float4*)(lnb + outb);
  float o0 = (vvv[0]-mean)*rsq*gv.x + bv.x;
  float o1 = (vvv[1]-mean)*rsq*gv.y + bv.y;
  float o2 = (vvv[2]-mean)*rsq*gv.z + bv.z;
  float o3 = (vvv[3]-mean)*rsq*gv.w + bv.w;
  *(float4*)(hout + (size_t)node*HID + outb) = make_float4(o0,o1,o2,o3);
  union { f16x2 h2[2]; uint2 u; } pk;
  pk.h2[0] = __builtin_amdgcn_cvt_pkrtz(o0,o1);
  pk.h2[1] = __builtin_amdgcn_cvt_pkrtz(o2,o3);
  *(uint2*)(hfout + (size_t)node*HID + outb) = pk.u;
  *(uint2*)(&HB[col][outb]) = pk.u;          // new h into LDS for UV GEMM

  // ---- phase D: next layer's UV GEMM (skipped on last layer) ----
  if (UVout){
    __syncthreads();
    f16x8 bf[4];
#pragma unroll
    for (int s=0;s<4;s++) bf[s] = *(const f16x8*)(&HB[col][s*32 + quad*8]);
    floatx4 au[4];
#pragma unroll
    for (int i=0;i<4;i++) au[i] = (floatx4)(0.f);
    const _Float16* wbn = wnfN + quad*128 + col*8;
#pragma unroll
    for (int s=0;s<4;s++)
#pragma unroll
      for (int mt=0;mt<4;mt++){
        f16x8 a = *(const f16x8*)(wbn + (size_t)((wv*4+mt)*4+s)*512);
        au[mt] = __builtin_amdgcn_mfma_f32_16x16x32_f16(a, bf[s], au[mt], 0,0,0);
      }
#pragma unroll
    for (int mt=0;mt<4;mt++){
      int o0i = (wv*4+mt)*16 + quad*4;
      float4 buv = *(const float4*)(biasUVn + o0i);
      union { f16x2 h2[2]; uint2 u; } pu;
      pu.h2[0] = __builtin_amdgcn_cvt_pkrtz(au[mt][0]+buv.x, au[mt][1]+buv.y);
      pu.h2[1] = __builtin_amdgcn_cvt_pkrtz(au[mt][2]+buv.z, au[mt][3]+buv.w);
      *(uint2*)(UVout + (size_t)node*512 + o0i) = pu.u;
    }
  }
}

// ---------------- pooling (binary search over sorted batch) + projector ----------------
__global__ void k_fin(const float* __restrict__ h, const int* __restrict__ batch,
    const float* __restrict__ p1W, const float* __restrict__ p1b,
    const float* __restrict__ l1g, const float* __restrict__ l1b,
    const float* __restrict__ p2W, const float* __restrict__ p2b,
    const float* __restrict__ l2g, const float* __restrict__ l2b,
    float* __restrict__ out){
  const int g = blockIdx.x, c = threadIdx.x;
  __shared__ float xg[HID], p[HID], red[4];
  int l=0, r=NN;
  while (l<r){ int m=(l+r)>>1; if (batch[m]<g) l=m+1; else r=m; }
  const int lo = l;
  r = NN;
  while (l<r){ int m=(l+r)>>1; if (batch[m]<g+1) l=m+1; else r=m; }
  const int hi = l;
  float cnt = (float)(hi-lo);
  float s = 0.f;
  int n = lo;
  for (; n+4<=hi; n+=4)
    s += h[n*HID+c] + h[(n+1)*HID+c] + h[(n+2)*HID+c] + h[(n+3)*HID+c];
  for (; n<hi; n++) s += h[n*HID+c];
  float xgv = s * (1.f/fmaxf(cnt,1.f) + 1.f/(cnt + 1e-6f));
  out[NG*64 + g*HID + c] = xgv;
  xg[c] = xgv;
  __syncthreads();
  float v = p1b[c];
  for (int k=0;k<HID;k++) v += xg[k]*p1W[c*HID + k];
  float sv=v, sv2=v*v;
#pragma unroll
  for (int m=1;m<64;m<<=1){ sv+=__shfl_xor(sv,m,64); sv2+=__shfl_xor(sv2,m,64); }
  if ((c&63)==0){ red[(c>>6)*2]=sv; red[(c>>6)*2+1]=sv2; }
  __syncthreads();
  float S=red[0]+red[2], S2=red[1]+red[3];
  float mean=S*(1.f/128.f), var=S2*(1.f/128.f)-mean*mean;
  float y=(v-mean)*rsqrtf(var+1e-5f)*l1g[c]+l1b[c];
  p[c] = y*fsig(y);
  __syncthreads();
  if (c < 64){
    float z = p2b[c];
    for (int k=0;k<HID;k++) z += p[k]*p2W[c*HID + k];
    float t=z, t2=z*z;
#pragma unroll
    for (int m=1;m<64;m<<=1){ t+=__shfl_xor(t,m,64); t2+=__shfl_xor(t2,m,64); }
    float mn=t*(1.f/64.f), vr=t2*(1.f/64.f)-mn*mn;
    out[g*64 + c] = (z-mn)*rsqrtf(vr+1e-5f)*l2g[c]+l2b[c];
  }
}

extern "C" void kernel_launch(void* const* d_in, const int* in_sizes, int n_in,
                              void* d_out, int out_size, void* d_ws, size_t ws_size,
                              hipStream_t stream){
  const float* x     = (const float*)d_in[0];
  const float* ea    = (const float*)d_in[1];
  const int*   ei    = (const int*)  d_in[2];
  const int*   batch = (const int*)  d_in[3];
  const float* embW  = (const float*)d_in[4];
  const float* embB  = (const float*)d_in[5];
  const float* embG  = (const float*)d_in[6];
  const float* embBe = (const float*)d_in[7];
  const float* m1W   = (const float*)d_in[8];
  const float* m1b   = (const float*)d_in[9];
  const float* m2W   = (const float*)d_in[10];
  const float* m2b   = (const float*)d_in[11];
  const float* gW    = (const float*)d_in[12];
  const float* gb    = (const float*)d_in[13];
  const float* lng   = (const float*)d_in[14];
  const float* lnb   = (const float*)d_in[15];
  const float* p1W   = (const float*)d_in[16];
  const float* p1b   = (const float*)d_in[17];
  const float* l1g   = (const float*)d_in[18];
  const float* l1b   = (const float*)d_in[19];
  const float* p2W   = (const float*)d_in[20];
  const float* p2b   = (const float*)d_in[21];
  const float* l2g   = (const float*)d_in[22];
  const float* l2b   = (const float*)d_in[23];

  char* p = (char*)d_ws;
  auto alloc = [&](size_t bytes){ char* r = p; p += (bytes + 255) & ~(size_t)255; return r; };
  float*     h    = (float*)     alloc((size_t)NNP*HID*4);
  _Float16*  hf   = (_Float16*)  alloc((size_t)NNP*HID*2);
  _Float16*  UVa  = (_Float16*)  alloc((size_t)NNP*512*2);
  _Float16*  UVb  = (_Float16*)  alloc((size_t)NNP*512*2);
  _Float16*  wnf  = (_Float16*)  alloc((size_t)NL*65536*2);
  _Float16*  w2f  = (_Float16*)  alloc((size_t)NL*32768*2);
  _Float16*  gwf  = (_Float16*)  alloc((size_t)NL*32768*2);
  float*     w256 = (float*)     alloc((size_t)NL*256*4);
  float*     biasUV=(float*)     alloc((size_t)NL*512*4);
  int*       deg  = (int*)       alloc((size_t)2*NNP*4);     // deg + cursor contiguous
  int*       cursor = deg + NNP;
  int*       rs   = (int*)       alloc((size_t)(NNP+1)*4);
  int*       esrc = (int*)       alloc((size_t)NE*4);
  float*     eas  = (float*)     alloc((size_t)NE*4);

  hipMemsetAsync(deg, 0, (size_t)2*NNP*4, stream);

  k_setup<<<SETUP_B + NNP/16, 256, 0, stream>>>(
      m1W, m2W, gW, m1b, wnf, w2f, gwf, w256, biasUV,
      ei, deg, x, embW, embB, embG, embBe, h, hf);
  k_scan<<<1, 256, 0, stream>>>(deg, rs);
  k_rank<<<NE/256, 256, 0, stream>>>(ei, ea, rs, cursor, esrc, eas);
  k_nodeUV<<<NNP/16, 256, 0, stream>>>(hf, wnf, biasUV, UVa);

  _Float16* uvin = UVa;
  _Float16* uvout = UVb;
  for (int l=0; l<NL; l++){
    bool last = (l == NL-1);
    k_layer<<<NNP/16, 512, 0, stream>>>(
        uvin, esrc, eas, rs, w256 + l*256,
        w2f + (size_t)l*32768, m2b + l*128,
        gwf + (size_t)l*32768, gb + l*128,
        lng + l*128, lnb + l*128,
        hf, h, h, hf,
        last ? nullptr : biasUV + (l+1)*512,
        last ? nullptr : wnf + (size_t)(l+1)*65536,
        last ? nullptr : uvout);
    _Float16* t = uvin; uvin = uvout; uvout = t;
  }
  k_fin<<<NG, 128, 0, stream>>>(h, batch, p1W, p1b, l1g, l1b,
                                p2W, p2b, l2g, l2b, (float*)d_out);
}